// Round 1
// baseline (338.880 us; speedup 1.0000x reference)
//
#include <hip/hip_runtime.h>
#include <hip/hip_bf16.h>
#include <math.h>

// Mamba block dims (fixed per reference)
#define BB 4
#define LL 2048
#define DMODEL 256
#define DINNER 512
#define DSTATE 16
#define DCONV 4
#define DTRANK 16
#define NXP 48            // DTRANK + 2*DSTATE
#define MROWS (BB*LL)     // 8192

// chunked scan config
#define NC 32
#define LC 64             // NC*LC == LL

// ---------------------------------------------------------------------------
// Generic fp32 GEMM, "NT" layout: C[m,n] = sum_k A[m*K+k] * B[n*K+k]
// 64x64 tile, 256 threads, 4x4 micro-tile per thread. Guards for ragged N.
// ---------------------------------------------------------------------------
__global__ __launch_bounds__(256) void gemm_nt(const float* __restrict__ A,
                                               const float* __restrict__ Bw,
                                               float* __restrict__ C,
                                               int M, int N, int K) {
    __shared__ float As[64][68];   // [k][m], row stride 272B (16B aligned)
    __shared__ float Bs[64][68];   // [k][n]
    const int tid = threadIdx.x;
    const int m0 = blockIdx.y * 64, n0 = blockIdx.x * 64;
    const int tx = tid & 15, ty = tid >> 4;
    const int kq = (tid & 15) * 4;   // loader: k offset
    const int rr = tid >> 4;         // loader: row 0..15 (+16 steps)

    float acc[4][4];
#pragma unroll
    for (int i = 0; i < 4; ++i)
#pragma unroll
        for (int j = 0; j < 4; ++j) acc[i][j] = 0.f;

    for (int k0 = 0; k0 < K; k0 += 64) {
#pragma unroll
        for (int r = 0; r < 4; ++r) {
            const int mm = rr + r * 16;
            const int gm = m0 + mm, gk = k0 + kq;
            float4 v = make_float4(0.f, 0.f, 0.f, 0.f);
            if (gm < M) v = *(const float4*)&A[(size_t)gm * K + gk];  // K % 64 == 0 always here
            As[kq + 0][mm] = v.x; As[kq + 1][mm] = v.y;
            As[kq + 2][mm] = v.z; As[kq + 3][mm] = v.w;

            const int gn = n0 + mm;
            float4 w = make_float4(0.f, 0.f, 0.f, 0.f);
            if (gn < N) w = *(const float4*)&Bw[(size_t)gn * K + gk];
            Bs[kq + 0][mm] = w.x; Bs[kq + 1][mm] = w.y;
            Bs[kq + 2][mm] = w.z; Bs[kq + 3][mm] = w.w;
        }
        __syncthreads();
#pragma unroll 4
        for (int kk = 0; kk < 64; ++kk) {
            const float4 a = *(const float4*)&As[kk][ty * 4];
            const float4 b = *(const float4*)&Bs[kk][tx * 4];
            acc[0][0] = fmaf(a.x, b.x, acc[0][0]); acc[0][1] = fmaf(a.x, b.y, acc[0][1]);
            acc[0][2] = fmaf(a.x, b.z, acc[0][2]); acc[0][3] = fmaf(a.x, b.w, acc[0][3]);
            acc[1][0] = fmaf(a.y, b.x, acc[1][0]); acc[1][1] = fmaf(a.y, b.y, acc[1][1]);
            acc[1][2] = fmaf(a.y, b.z, acc[1][2]); acc[1][3] = fmaf(a.y, b.w, acc[1][3]);
            acc[2][0] = fmaf(a.z, b.x, acc[2][0]); acc[2][1] = fmaf(a.z, b.y, acc[2][1]);
            acc[2][2] = fmaf(a.z, b.z, acc[2][2]); acc[2][3] = fmaf(a.z, b.w, acc[2][3]);
            acc[3][0] = fmaf(a.w, b.x, acc[3][0]); acc[3][1] = fmaf(a.w, b.y, acc[3][1]);
            acc[3][2] = fmaf(a.w, b.z, acc[3][2]); acc[3][3] = fmaf(a.w, b.w, acc[3][3]);
        }
        __syncthreads();
    }

    if (n0 + 64 <= N) {  // fast path: full tile in N (M always divides 64 here)
#pragma unroll
        for (int i = 0; i < 4; ++i) {
            float4 v = make_float4(acc[i][0], acc[i][1], acc[i][2], acc[i][3]);
            *(float4*)&C[(size_t)(m0 + ty * 4 + i) * N + n0 + tx * 4] = v;
        }
    } else {
#pragma unroll
        for (int i = 0; i < 4; ++i)
#pragma unroll
            for (int j = 0; j < 4; ++j) {
                const int n = n0 + tx * 4 + j;
                if (n < N) C[(size_t)(m0 + ty * 4 + i) * N + n] = acc[i][j];
            }
    }
}

// ---------------------------------------------------------------------------
// causal depthwise conv1d (k=4) + bias + SiLU over the u-half of xz
// one thread per (b,t,d)
// ---------------------------------------------------------------------------
__global__ __launch_bounds__(256) void conv_silu(const float* __restrict__ xz,
                                                 const float* __restrict__ cw,
                                                 const float* __restrict__ cb,
                                                 float* __restrict__ u) {
    const int g = blockIdx.x * 256 + threadIdx.x;  // over BB*LL*DINNER
    const int d = g & (DINNER - 1);
    const int t = (g >> 9) & (LL - 1);
    const int b = g >> 20;
    const float w0 = cw[d * 4 + 0], w1 = cw[d * 4 + 1], w2 = cw[d * 4 + 2], w3 = cw[d * 4 + 3];
    const size_t base = ((size_t)(b * LL + t)) * (2 * DINNER) + d;
    float s = cb[d] + xz[base] * w3;
    if (t >= 1) s = fmaf(xz[base - 1024], w2, s);
    if (t >= 2) s = fmaf(xz[base - 2048], w1, s);
    if (t >= 3) s = fmaf(xz[base - 3072], w0, s);
    u[g] = s / (1.f + expf(-s));
}

// ---------------------------------------------------------------------------
// delta = softplus(x_dbl[:, :16] @ W_dt^T + b_dt); one thread per (row, d)
// ---------------------------------------------------------------------------
__global__ __launch_bounds__(256) void dt_softplus(const float* __restrict__ x_dbl,
                                                   const float* __restrict__ W_dt,
                                                   const float* __restrict__ b_dt,
                                                   float* __restrict__ delta) {
    const int g = blockIdx.x * 256 + threadIdx.x;  // over MROWS*DINNER
    const int d = g & (DINNER - 1);
    const int row = g >> 9;
    const float* xr = &x_dbl[(size_t)row * NXP];
    const float4* wr = (const float4*)&W_dt[d * DTRANK];
    float s = b_dt[d];
#pragma unroll
    for (int i = 0; i < 4; ++i) {
        const float4 w = wr[i];
        s = fmaf(xr[i * 4 + 0], w.x, s);
        s = fmaf(xr[i * 4 + 1], w.y, s);
        s = fmaf(xr[i * 4 + 2], w.z, s);
        s = fmaf(xr[i * 4 + 3], w.w, s);
    }
    delta[g] = (s > 20.f) ? s : log1pf(expf(s));
}

// ---------------------------------------------------------------------------
// chunked selective scan
// thread index bits: n(4) d(9) c(5) b(2)
// ---------------------------------------------------------------------------
__global__ __launch_bounds__(256) void scan_a(const float* __restrict__ delta,
                                              const float* __restrict__ u,
                                              const float* __restrict__ x_dbl,
                                              const float* __restrict__ A_log,
                                              float* __restrict__ a_cum,
                                              float* __restrict__ h_end) {
    const int g = blockIdx.x * 256 + threadIdx.x;
    const int n = g & 15, d = (g >> 4) & 511, c = (g >> 13) & 31, b = g >> 18;
    const float An = -expf(A_log[d * 16 + n]);
    float h = 0.f, ap = 1.f;
    const size_t row0 = (size_t)b * LL + c * LC;
    for (int i = 0; i < LC; ++i) {
        const size_t row = row0 + i;
        const float dlt = delta[row * DINNER + d];
        const float uu = u[row * DINNER + d];
        const float bb = x_dbl[row * NXP + DTRANK + n];
        const float dA = __expf(dlt * An);
        ap *= dA;
        h = fmaf(dA, h, dlt * uu * bb);
    }
    const int idx = ((c * 4 + b) * 512 + d) * 16 + n;
    a_cum[idx] = ap;
    h_end[idx] = h;
}

__global__ __launch_bounds__(256) void scan_b(const float* __restrict__ a_cum,
                                              const float* __restrict__ h_end,
                                              float* __restrict__ h_start) {
    const int g = blockIdx.x * 256 + threadIdx.x;  // BB*DINNER*DSTATE = 32768
    const int n = g & 15, d = (g >> 4) & 511, b = g >> 13;
    float hs = 0.f;
    for (int c = 0; c < NC; ++c) {
        const int idx = ((c * 4 + b) * 512 + d) * 16 + n;
        h_start[idx] = hs;
        hs = fmaf(a_cum[idx], hs, h_end[idx]);
    }
}

__global__ __launch_bounds__(256) void scan_c(const float* __restrict__ delta,
                                              const float* __restrict__ u,
                                              const float* __restrict__ x_dbl,
                                              const float* __restrict__ A_log,
                                              const float* __restrict__ Dskip,
                                              const float* __restrict__ xz,
                                              const float* __restrict__ h_start,
                                              float* __restrict__ yg) {
    const int g = blockIdx.x * 256 + threadIdx.x;
    const int n = g & 15, d = (g >> 4) & 511, c = (g >> 13) & 31, b = g >> 18;
    const float An = -expf(A_log[d * 16 + n]);
    float h = h_start[((c * 4 + b) * 512 + d) * 16 + n];
    const float dsk = Dskip[d];
    const size_t row0 = (size_t)b * LL + c * LC;
    for (int i = 0; i < LC; ++i) {
        const size_t row = row0 + i;
        const float dlt = delta[row * DINNER + d];
        const float uu = u[row * DINNER + d];
        const float bb = x_dbl[row * NXP + DTRANK + n];
        const float cc = x_dbl[row * NXP + DTRANK + DSTATE + n];
        const float dA = __expf(dlt * An);
        h = fmaf(dA, h, dlt * uu * bb);
        float yp = h * cc;
        yp += __shfl_xor(yp, 1);
        yp += __shfl_xor(yp, 2);
        yp += __shfl_xor(yp, 4);
        yp += __shfl_xor(yp, 8);
        if (n == 0) {
            const float zz = xz[row * (2 * DINNER) + DINNER + d];
            const float yv = fmaf(uu, dsk, yp);
            yg[row * DINNER + d] = yv * (zz / (1.f + __expf(-zz)));
        }
    }
}

// ---------------------------------------------------------------------------
extern "C" void kernel_launch(void* const* d_in, const int* in_sizes, int n_in,
                              void* d_out, int out_size, void* d_ws, size_t ws_size,
                              hipStream_t stream) {
    const float* x      = (const float*)d_in[0];
    const float* W_in   = (const float*)d_in[1];
    const float* conv_w = (const float*)d_in[2];
    const float* conv_b = (const float*)d_in[3];
    const float* W_xp   = (const float*)d_in[4];
    const float* W_dt   = (const float*)d_in[5];
    const float* b_dt   = (const float*)d_in[6];
    const float* A_log  = (const float*)d_in[7];
    const float* Dskip  = (const float*)d_in[8];
    const float* W_out  = (const float*)d_in[9];
    float* out = (float*)d_out;

    float* ws = (float*)d_ws;
    // workspace layout (floats); total ~24.5M floats = 98 MB
    float* xz      = ws;                          // MROWS*1024
    float* u       = xz + (size_t)MROWS * 1024;   // MROWS*512
    float* x_dbl   = u + (size_t)MROWS * 512;     // MROWS*48
    float* delta   = x_dbl + (size_t)MROWS * 48;  // MROWS*512
    float* a_cum   = delta + (size_t)MROWS * 512; // NC*BB*512*16 = 1,048,576
    float* h_end   = a_cum + (size_t)NC * BB * 512 * 16;
    float* h_start = h_end + (size_t)NC * BB * 512 * 16;
    float* yg      = h_start + (size_t)NC * BB * 512 * 16;  // MROWS*512

    // 1) in_proj: xz = x @ W_in^T   [8192,1024] = [8192,256]@[1024,256]^T
    {
        dim3 grid(1024 / 64, MROWS / 64);
        gemm_nt<<<grid, 256, 0, stream>>>(x, W_in, xz, MROWS, 1024, DMODEL);
    }
    // 2) depthwise causal conv + SiLU -> u
    conv_silu<<<(BB * LL * DINNER) / 256, 256, 0, stream>>>(xz, conv_w, conv_b, u);
    // 3) x_proj: x_dbl = u @ W_xproj^T  [8192,48] = [8192,512]@[48,512]^T
    {
        dim3 grid((NXP + 63) / 64, MROWS / 64);
        gemm_nt<<<grid, 256, 0, stream>>>(u, W_xp, x_dbl, MROWS, NXP, DINNER);
    }
    // 4) delta = softplus(dt @ W_dt^T + b_dt)
    dt_softplus<<<(MROWS * DINNER) / 256, 256, 0, stream>>>(x_dbl, W_dt, b_dt, delta);
    // 5-7) chunked selective scan + gating
    scan_a<<<(BB * NC * DINNER * DSTATE) / 256, 256, 0, stream>>>(delta, u, x_dbl, A_log, a_cum, h_end);
    scan_b<<<(BB * DINNER * DSTATE) / 256, 256, 0, stream>>>(a_cum, h_end, h_start);
    scan_c<<<(BB * NC * DINNER * DSTATE) / 256, 256, 0, stream>>>(delta, u, x_dbl, A_log, Dskip, xz,
                                                                 h_start, yg);
    // 8) out_proj: out = yg @ W_out^T  [8192,256] = [8192,512]@[256,512]^T
    {
        dim3 grid(DMODEL / 64, MROWS / 64);
        gemm_nt<<<grid, 256, 0, stream>>>(yg, W_out, out, MROWS, DMODEL, DINNER);
    }
}

// Round 2
// 255.944 us; speedup vs baseline: 1.3240x; 1.3240x over previous
//
#include <hip/hip_runtime.h>
#include <hip/hip_bf16.h>
#include <math.h>

// Mamba block dims (fixed per reference)
#define BB 4
#define LL 2048
#define DMODEL 256
#define DINNER 512
#define DSTATE 16
#define DCONV 4
#define DTRANK 16
#define NXP 48            // DTRANK + 2*DSTATE
#define MROWS (BB*LL)     // 8192

// chunked scan config
#define NC 64
#define LC 32             // NC*LC == LL

// ---------------------------------------------------------------------------
// Generic fp32 GEMM, "NT" layout: C[m,n] = sum_k A[m*K+k] * B[n*K+k]
// 64x64 tile, 256 threads, 4x4 micro-tile per thread. Guards for ragged N.
// ---------------------------------------------------------------------------
__global__ __launch_bounds__(256) void gemm_nt(const float* __restrict__ A,
                                               const float* __restrict__ Bw,
                                               float* __restrict__ C,
                                               int M, int N, int K) {
    __shared__ float As[64][68];   // [k][m]
    __shared__ float Bs[64][68];   // [k][n]
    const int tid = threadIdx.x;
    const int m0 = blockIdx.y * 64, n0 = blockIdx.x * 64;
    const int tx = tid & 15, ty = tid >> 4;
    const int kq = (tid & 15) * 4;   // loader: k offset
    const int rr = tid >> 4;         // loader: row 0..15 (+16 steps)

    float acc[4][4];
#pragma unroll
    for (int i = 0; i < 4; ++i)
#pragma unroll
        for (int j = 0; j < 4; ++j) acc[i][j] = 0.f;

    for (int k0 = 0; k0 < K; k0 += 64) {
#pragma unroll
        for (int r = 0; r < 4; ++r) {
            const int mm = rr + r * 16;
            const int gm = m0 + mm, gk = k0 + kq;
            float4 v = make_float4(0.f, 0.f, 0.f, 0.f);
            if (gm < M) v = *(const float4*)&A[(size_t)gm * K + gk];
            As[kq + 0][mm] = v.x; As[kq + 1][mm] = v.y;
            As[kq + 2][mm] = v.z; As[kq + 3][mm] = v.w;

            const int gn = n0 + mm;
            float4 w = make_float4(0.f, 0.f, 0.f, 0.f);
            if (gn < N) w = *(const float4*)&Bw[(size_t)gn * K + gk];
            Bs[kq + 0][mm] = w.x; Bs[kq + 1][mm] = w.y;
            Bs[kq + 2][mm] = w.z; Bs[kq + 3][mm] = w.w;
        }
        __syncthreads();
#pragma unroll 4
        for (int kk = 0; kk < 64; ++kk) {
            const float4 a = *(const float4*)&As[kk][ty * 4];
            const float4 b = *(const float4*)&Bs[kk][tx * 4];
            acc[0][0] = fmaf(a.x, b.x, acc[0][0]); acc[0][1] = fmaf(a.x, b.y, acc[0][1]);
            acc[0][2] = fmaf(a.x, b.z, acc[0][2]); acc[0][3] = fmaf(a.x, b.w, acc[0][3]);
            acc[1][0] = fmaf(a.y, b.x, acc[1][0]); acc[1][1] = fmaf(a.y, b.y, acc[1][1]);
            acc[1][2] = fmaf(a.y, b.z, acc[1][2]); acc[1][3] = fmaf(a.y, b.w, acc[1][3]);
            acc[2][0] = fmaf(a.z, b.x, acc[2][0]); acc[2][1] = fmaf(a.z, b.y, acc[2][1]);
            acc[2][2] = fmaf(a.z, b.z, acc[2][2]); acc[2][3] = fmaf(a.z, b.w, acc[2][3]);
            acc[3][0] = fmaf(a.w, b.x, acc[3][0]); acc[3][1] = fmaf(a.w, b.y, acc[3][1]);
            acc[3][2] = fmaf(a.w, b.z, acc[3][2]); acc[3][3] = fmaf(a.w, b.w, acc[3][3]);
        }
        __syncthreads();
    }

    if (n0 + 64 <= N) {
#pragma unroll
        for (int i = 0; i < 4; ++i) {
            float4 v = make_float4(acc[i][0], acc[i][1], acc[i][2], acc[i][3]);
            *(float4*)&C[(size_t)(m0 + ty * 4 + i) * N + n0 + tx * 4] = v;
        }
    } else {
#pragma unroll
        for (int i = 0; i < 4; ++i)
#pragma unroll
            for (int j = 0; j < 4; ++j) {
                const int n = n0 + tx * 4 + j;
                if (n < N) C[(size_t)(m0 + ty * 4 + i) * N + n] = acc[i][j];
            }
    }
}

// ---------------------------------------------------------------------------
// causal depthwise conv1d (k=4) + bias + SiLU over the u-half of xz
// ---------------------------------------------------------------------------
__global__ __launch_bounds__(256) void conv_silu(const float* __restrict__ xz,
                                                 const float* __restrict__ cw,
                                                 const float* __restrict__ cb,
                                                 float* __restrict__ u) {
    const int g = blockIdx.x * 256 + threadIdx.x;  // over BB*LL*DINNER
    const int d = g & (DINNER - 1);
    const int t = (g >> 9) & (LL - 1);
    const int b = g >> 20;
    const float w0 = cw[d * 4 + 0], w1 = cw[d * 4 + 1], w2 = cw[d * 4 + 2], w3 = cw[d * 4 + 3];
    const size_t base = ((size_t)(b * LL + t)) * (2 * DINNER) + d;
    float s = cb[d] + xz[base] * w3;
    if (t >= 1) s = fmaf(xz[base - 1024], w2, s);
    if (t >= 2) s = fmaf(xz[base - 2048], w1, s);
    if (t >= 3) s = fmaf(xz[base - 3072], w0, s);
    u[g] = s / (1.f + expf(-s));
}

// ---------------------------------------------------------------------------
// delta = softplus(x_dbl[:, :16] @ W_dt^T + b_dt)
// ---------------------------------------------------------------------------
__global__ __launch_bounds__(256) void dt_softplus(const float* __restrict__ x_dbl,
                                                   const float* __restrict__ W_dt,
                                                   const float* __restrict__ b_dt,
                                                   float* __restrict__ delta) {
    const int g = blockIdx.x * 256 + threadIdx.x;  // over MROWS*DINNER
    const int d = g & (DINNER - 1);
    const int row = g >> 9;
    const float* xr = &x_dbl[(size_t)row * NXP];
    const float4* wr = (const float4*)&W_dt[d * DTRANK];
    float s = b_dt[d];
#pragma unroll
    for (int i = 0; i < 4; ++i) {
        const float4 w = wr[i];
        s = fmaf(xr[i * 4 + 0], w.x, s);
        s = fmaf(xr[i * 4 + 1], w.y, s);
        s = fmaf(xr[i * 4 + 2], w.z, s);
        s = fmaf(xr[i * 4 + 3], w.w, s);
    }
    delta[g] = (s > 20.f) ? s : log1pf(expf(s));
}

// ---------------------------------------------------------------------------
// chunked selective scan, one thread per (b,c,d); 16 states in registers.
// thread mapping: d = g&511, bc = g>>9, b = bc&3, c = bc>>2
// A wave = 64 consecutive d for one (b,c) -> B/C loads are wave-uniform.
// ---------------------------------------------------------------------------
__global__ __launch_bounds__(256) void scan_a(const float* __restrict__ delta,
                                              const float* __restrict__ u,
                                              const float* __restrict__ x_dbl,
                                              const float* __restrict__ A_log,
                                              float* __restrict__ a_cum,
                                              float* __restrict__ h_end) {
    const int g = blockIdx.x * 256 + threadIdx.x;
    const int d = g & 511, bc = g >> 9;
    const int b = bc & 3, c = bc >> 2;

    float An[16];
    {
        const float4* ap = (const float4*)&A_log[d * 16];
#pragma unroll
        for (int q = 0; q < 4; ++q) {
            const float4 v = ap[q];
            An[q * 4 + 0] = -expf(v.x); An[q * 4 + 1] = -expf(v.y);
            An[q * 4 + 2] = -expf(v.z); An[q * 4 + 3] = -expf(v.w);
        }
    }
    float h[16];
#pragma unroll
    for (int n = 0; n < 16; ++n) h[n] = 0.f;
    float sumd = 0.f;

    const size_t row0 = (size_t)b * LL + (size_t)c * LC;
    // prefetch step 0
    float pd = delta[row0 * DINNER + d];
    float pu = u[row0 * DINNER + d];
    float4 pB[4];
    {
        const float4* bp = (const float4*)&x_dbl[row0 * NXP + DTRANK];
#pragma unroll
        for (int q = 0; q < 4; ++q) pB[q] = bp[q];
    }

    for (int i = 0; i < LC; ++i) {
        const float dlt = pd, uu = pu;
        float Bv[16] = {pB[0].x, pB[0].y, pB[0].z, pB[0].w,
                        pB[1].x, pB[1].y, pB[1].z, pB[1].w,
                        pB[2].x, pB[2].y, pB[2].z, pB[2].w,
                        pB[3].x, pB[3].y, pB[3].z, pB[3].w};
        if (i + 1 < LC) {  // wave-uniform branch
            const size_t row = row0 + i + 1;
            pd = delta[row * DINNER + d];
            pu = u[row * DINNER + d];
            const float4* bp = (const float4*)&x_dbl[row * NXP + DTRANK];
#pragma unroll
            for (int q = 0; q < 4; ++q) pB[q] = bp[q];
        }
        sumd += dlt;
        const float du = dlt * uu;
#pragma unroll
        for (int n = 0; n < 16; ++n)
            h[n] = fmaf(__expf(dlt * An[n]), h[n], du * Bv[n]);
    }

    const size_t o = ((size_t)(c * BB + b) * DINNER + d) * 16;
#pragma unroll
    for (int q = 0; q < 4; ++q) {
        // chunk decay product = exp(An * sum(delta)) — exact product identity
        *(float4*)&a_cum[o + q * 4] = make_float4(
            __expf(An[q * 4 + 0] * sumd), __expf(An[q * 4 + 1] * sumd),
            __expf(An[q * 4 + 2] * sumd), __expf(An[q * 4 + 3] * sumd));
        *(float4*)&h_end[o + q * 4] = make_float4(h[q * 4 + 0], h[q * 4 + 1],
                                                  h[q * 4 + 2], h[q * 4 + 3]);
    }
}

__global__ __launch_bounds__(256) void scan_b(const float* __restrict__ a_cum,
                                              const float* __restrict__ h_end,
                                              float* __restrict__ h_start) {
    const int g = blockIdx.x * 256 + threadIdx.x;  // BB*DINNER*DSTATE = 32768
    const int n = g & 15, d = (g >> 4) & 511, b = g >> 13;
    float hs = 0.f;
#pragma unroll 8
    for (int c = 0; c < NC; ++c) {
        const size_t idx = ((size_t)(c * BB + b) * DINNER + d) * 16 + n;
        h_start[idx] = hs;
        hs = fmaf(a_cum[idx], hs, h_end[idx]);
    }
}

// NOTE: yg may alias delta (each (row,d) is read strictly before its owning
// thread writes it; no other consumer of delta remains) — no __restrict__ here.
__global__ __launch_bounds__(256) void scan_c(const float* delta,
                                              const float* __restrict__ u,
                                              const float* __restrict__ x_dbl,
                                              const float* __restrict__ A_log,
                                              const float* __restrict__ Dskip,
                                              const float* __restrict__ xz,
                                              const float* __restrict__ h_start,
                                              float* yg) {
    const int g = blockIdx.x * 256 + threadIdx.x;
    const int d = g & 511, bc = g >> 9;
    const int b = bc & 3, c = bc >> 2;

    float An[16];
    {
        const float4* ap = (const float4*)&A_log[d * 16];
#pragma unroll
        for (int q = 0; q < 4; ++q) {
            const float4 v = ap[q];
            An[q * 4 + 0] = -expf(v.x); An[q * 4 + 1] = -expf(v.y);
            An[q * 4 + 2] = -expf(v.z); An[q * 4 + 3] = -expf(v.w);
        }
    }
    float h[16];
    {
        const size_t o = ((size_t)(c * BB + b) * DINNER + d) * 16;
#pragma unroll
        for (int q = 0; q < 4; ++q) {
            const float4 v = *(const float4*)&h_start[o + q * 4];
            h[q * 4 + 0] = v.x; h[q * 4 + 1] = v.y; h[q * 4 + 2] = v.z; h[q * 4 + 3] = v.w;
        }
    }
    const float dsk = Dskip[d];

    const size_t row0 = (size_t)b * LL + (size_t)c * LC;
    // prefetch step 0
    float pd = delta[row0 * DINNER + d];
    float pu = u[row0 * DINNER + d];
    float pz = xz[row0 * (2 * DINNER) + DINNER + d];
    float4 pB[4], pC[4];
    {
        const float4* bp = (const float4*)&x_dbl[row0 * NXP + DTRANK];
#pragma unroll
        for (int q = 0; q < 4; ++q) pB[q] = bp[q];
#pragma unroll
        for (int q = 0; q < 4; ++q) pC[q] = bp[4 + q];
    }

    for (int i = 0; i < LC; ++i) {
        const size_t crow = row0 + i;
        const float dlt = pd, uu = pu, zz = pz;
        float Bv[16] = {pB[0].x, pB[0].y, pB[0].z, pB[0].w,
                        pB[1].x, pB[1].y, pB[1].z, pB[1].w,
                        pB[2].x, pB[2].y, pB[2].z, pB[2].w,
                        pB[3].x, pB[3].y, pB[3].z, pB[3].w};
        float Cv[16] = {pC[0].x, pC[0].y, pC[0].z, pC[0].w,
                        pC[1].x, pC[1].y, pC[1].z, pC[1].w,
                        pC[2].x, pC[2].y, pC[2].z, pC[2].w,
                        pC[3].x, pC[3].y, pC[3].z, pC[3].w};
        if (i + 1 < LC) {  // wave-uniform branch
            const size_t row = crow + 1;
            pd = delta[row * DINNER + d];
            pu = u[row * DINNER + d];
            pz = xz[row * (2 * DINNER) + DINNER + d];
            const float4* bp = (const float4*)&x_dbl[row * NXP + DTRANK];
#pragma unroll
            for (int q = 0; q < 4; ++q) pB[q] = bp[q];
#pragma unroll
            for (int q = 0; q < 4; ++q) pC[q] = bp[4 + q];
        }
        const float du = dlt * uu;
#pragma unroll
        for (int n = 0; n < 16; ++n)
            h[n] = fmaf(__expf(dlt * An[n]), h[n], du * Bv[n]);
        float y = 0.f;
#pragma unroll
        for (int n = 0; n < 16; ++n) y = fmaf(h[n], Cv[n], y);
        y = fmaf(uu, dsk, y);
        const float sz = zz / (1.f + __expf(-zz));
        yg[crow * DINNER + d] = y * sz;
    }
}

// ---------------------------------------------------------------------------
extern "C" void kernel_launch(void* const* d_in, const int* in_sizes, int n_in,
                              void* d_out, int out_size, void* d_ws, size_t ws_size,
                              hipStream_t stream) {
    const float* x      = (const float*)d_in[0];
    const float* W_in   = (const float*)d_in[1];
    const float* conv_w = (const float*)d_in[2];
    const float* conv_b = (const float*)d_in[3];
    const float* W_xp   = (const float*)d_in[4];
    const float* W_dt   = (const float*)d_in[5];
    const float* b_dt   = (const float*)d_in[6];
    const float* A_log  = (const float*)d_in[7];
    const float* Dskip  = (const float*)d_in[8];
    const float* W_out  = (const float*)d_in[9];
    float* out = (float*)d_out;

    float* ws = (float*)d_ws;
    // workspace layout (floats); ~94 MB total
    float* xz      = ws;                          // MROWS*1024
    float* u       = xz + (size_t)MROWS * 1024;   // MROWS*512
    float* x_dbl   = u + (size_t)MROWS * 512;     // MROWS*48
    float* delta   = x_dbl + (size_t)MROWS * 48;  // MROWS*512
    float* a_cum   = delta + (size_t)MROWS * 512; // NC*BB*512*16 = 2,097,152
    float* h_end   = a_cum + (size_t)NC * BB * 512 * 16;
    float* h_start = h_end + (size_t)NC * BB * 512 * 16;
    float* yg      = delta;                       // aliased (safe, see scan_c)

    // 1) in_proj: xz = x @ W_in^T   [8192,1024] = [8192,256]@[1024,256]^T
    {
        dim3 grid(1024 / 64, MROWS / 64);
        gemm_nt<<<grid, 256, 0, stream>>>(x, W_in, xz, MROWS, 1024, DMODEL);
    }
    // 2) depthwise causal conv + SiLU -> u
    conv_silu<<<(BB * LL * DINNER) / 256, 256, 0, stream>>>(xz, conv_w, conv_b, u);
    // 3) x_proj: x_dbl = u @ W_xproj^T  [8192,48] = [8192,512]@[48,512]^T
    {
        dim3 grid((NXP + 63) / 64, MROWS / 64);
        gemm_nt<<<grid, 256, 0, stream>>>(u, W_xp, x_dbl, MROWS, NXP, DINNER);
    }
    // 4) delta = softplus(dt @ W_dt^T + b_dt)
    dt_softplus<<<(MROWS * DINNER) / 256, 256, 0, stream>>>(x_dbl, W_dt, b_dt, delta);
    // 5-7) chunked selective scan + gating (one thread per (b,c,d))
    scan_a<<<(BB * NC * DINNER) / 256, 256, 0, stream>>>(delta, u, x_dbl, A_log, a_cum, h_end);
    scan_b<<<(BB * DINNER * DSTATE) / 256, 256, 0, stream>>>(a_cum, h_end, h_start);
    scan_c<<<(BB * NC * DINNER) / 256, 256, 0, stream>>>(delta, u, x_dbl, A_log, Dskip, xz,
                                                         h_start, yg);
    // 8) out_proj: out = yg @ W_out^T  [8192,256] = [8192,512]@[256,512]^T
    {
        dim3 grid(DMODEL / 64, MROWS / 64);
        gemm_nt<<<grid, 256, 0, stream>>>(yg, W_out, out, MROWS, DMODEL, DINNER);
    }
}

// Round 3
// 167.110 us; speedup vs baseline: 2.0279x; 1.5316x over previous
//
#include <hip/hip_runtime.h>
#include <hip/hip_bf16.h>
#include <math.h>

// Mamba block dims (fixed per reference)
#define BB 4
#define LL 2048
#define DMODEL 256
#define DINNER 512
#define DSTATE 16
#define DCONV 4
#define DTRANK 16
#define NXP 48            // DTRANK + 2*DSTATE
#define MROWS (BB*LL)     // 8192

// chunked scan config
#define NC 64
#define LC 32             // NC*LC == LL

typedef __attribute__((ext_vector_type(8))) short short8;   // 8 bf16 (4 VGPR)
typedef __attribute__((ext_vector_type(4))) float floatx4;  // MFMA accumulator

// round-to-nearest-even fp32 -> bf16 bits
static __device__ __forceinline__ ushort f2bf(float f) {
    unsigned u = __builtin_bit_cast(unsigned, f);
    unsigned r = (u + 0x7FFFu + ((u >> 16) & 1u)) >> 16;
    return (ushort)r;
}

// ---------------------------------------------------------------------------
// fp32 -> bf16 bulk convert (float4 in, ushort4 out)
// ---------------------------------------------------------------------------
__global__ __launch_bounds__(256) void f2b4(const float* __restrict__ s,
                                            ushort* __restrict__ d, int n4) {
    const int i = blockIdx.x * 256 + threadIdx.x;
    if (i < n4) {
        const float4 v = ((const float4*)s)[i];
        ushort4 o;
        o.x = f2bf(v.x); o.y = f2bf(v.y); o.z = f2bf(v.z); o.w = f2bf(v.w);
        ((ushort4*)d)[i] = o;
    }
}

// ---------------------------------------------------------------------------
// bf16 MFMA GEMM, NT: C[m,n] = sum_k A[m,k]*B[n,k]; A[M,K],B[N,K] bf16, C fp32
// block = 4 waves (2x2), wave tile 64x32 (4x2 MFMA 16x16x32), frags direct
// from global (no LDS). GUARD=1 adds N-bounds on B loads + C stores.
// ---------------------------------------------------------------------------
template <int GUARD>
__global__ __launch_bounds__(256) void gemm_bf16_nt(const ushort* __restrict__ A,
                                                    const ushort* __restrict__ Bw,
                                                    float* __restrict__ C,
                                                    int M, int N, int K) {
    const int tid = threadIdx.x;
    const int lane = tid & 63, wid = tid >> 6;
    const int wr = wid >> 1, wc = wid & 1;
    const int m0 = blockIdx.y * 128 + wr * 64;
    const int n0 = blockIdx.x * 64 + wc * 32;
    const int r = lane & 15, kh = lane >> 4;   // frag row, k-group

    const ushort* Ap = A + (size_t)(m0 + r) * K + kh * 8;
    const ushort* Bp = Bw + (size_t)(n0 + r) * K + kh * 8;
    bool bok0 = true, bok1 = true;
    if (GUARD) { bok0 = (n0 + r) < N; bok1 = (n0 + 16 + r) < N; }

    floatx4 acc[4][2];
#pragma unroll
    for (int i = 0; i < 4; ++i)
#pragma unroll
        for (int j = 0; j < 2; ++j) acc[i][j] = (floatx4){0.f, 0.f, 0.f, 0.f};

    const short8 zfrag = {0, 0, 0, 0, 0, 0, 0, 0};
    short8 a0[4], b0[2], a1[4], b1[2];

#define LDSET(av, bv, koff)                                                     \
    do {                                                                        \
        _Pragma("unroll") for (int ti = 0; ti < 4; ++ti)                        \
            av[ti] = *(const short8*)(Ap + (size_t)ti * 16 * K + (koff));       \
        bv[0] = (!GUARD || bok0) ? *(const short8*)(Bp + (koff)) : zfrag;       \
        bv[1] = (!GUARD || bok1) ? *(const short8*)(Bp + 16 * (size_t)K + (koff)) : zfrag; \
    } while (0)

#define DOMFMA(av, bv)                                                          \
    do {                                                                        \
        _Pragma("unroll") for (int ti = 0; ti < 4; ++ti)                        \
            _Pragma("unroll") for (int nt = 0; nt < 2; ++nt)                    \
                acc[ti][nt] = __builtin_amdgcn_mfma_f32_16x16x32_bf16(          \
                    av[ti], bv[nt], acc[ti][nt], 0, 0, 0);                      \
    } while (0)

    LDSET(a0, b0, 0);
    for (int k0 = 0; k0 < K; k0 += 64) {
        LDSET(a1, b1, k0 + 32);
        DOMFMA(a0, b0);
        if (k0 + 64 < K) LDSET(a0, b0, k0 + 64);
        DOMFMA(a1, b1);
    }
#undef LDSET
#undef DOMFMA

    const int cr = (lane >> 4) * 4;   // C row offset in tile
    const int cc = lane & 15;         // C col in tile
#pragma unroll
    for (int ti = 0; ti < 4; ++ti)
#pragma unroll
        for (int nt = 0; nt < 2; ++nt) {
            const int col = n0 + nt * 16 + cc;
            if (GUARD && col >= N) continue;
#pragma unroll
            for (int j = 0; j < 4; ++j)
                C[(size_t)(m0 + ti * 16 + cr + j) * N + col] = acc[ti][nt][j];
        }
}

// ---------------------------------------------------------------------------
// causal depthwise conv1d (k=4) + bias + SiLU; writes fp32 u and bf16 u
// ---------------------------------------------------------------------------
__global__ __launch_bounds__(256) void conv_silu(const float* __restrict__ xz,
                                                 const float* __restrict__ cw,
                                                 const float* __restrict__ cb,
                                                 float* __restrict__ u,
                                                 ushort* __restrict__ ub) {
    const int g = blockIdx.x * 256 + threadIdx.x;  // over BB*LL*DINNER
    const int d = g & (DINNER - 1);
    const int t = (g >> 9) & (LL - 1);
    const int b = g >> 20;
    const float w0 = cw[d * 4 + 0], w1 = cw[d * 4 + 1], w2 = cw[d * 4 + 2], w3 = cw[d * 4 + 3];
    const size_t base = ((size_t)(b * LL + t)) * (2 * DINNER) + d;
    float s = cb[d] + xz[base] * w3;
    if (t >= 1) s = fmaf(xz[base - 1024], w2, s);
    if (t >= 2) s = fmaf(xz[base - 2048], w1, s);
    if (t >= 3) s = fmaf(xz[base - 3072], w0, s);
    const float res = s / (1.f + expf(-s));
    u[g] = res;
    ub[g] = f2bf(res);
}

// ---------------------------------------------------------------------------
// delta = softplus(x_dbl[:, :16] @ W_dt^T + b_dt)
// ---------------------------------------------------------------------------
__global__ __launch_bounds__(256) void dt_softplus(const float* __restrict__ x_dbl,
                                                   const float* __restrict__ W_dt,
                                                   const float* __restrict__ b_dt,
                                                   float* __restrict__ delta) {
    const int g = blockIdx.x * 256 + threadIdx.x;  // over MROWS*DINNER
    const int d = g & (DINNER - 1);
    const int row = g >> 9;
    const float* xr = &x_dbl[(size_t)row * NXP];
    const float4* wr = (const float4*)&W_dt[d * DTRANK];
    float s = b_dt[d];
#pragma unroll
    for (int i = 0; i < 4; ++i) {
        const float4 w = wr[i];
        s = fmaf(xr[i * 4 + 0], w.x, s);
        s = fmaf(xr[i * 4 + 1], w.y, s);
        s = fmaf(xr[i * 4 + 2], w.z, s);
        s = fmaf(xr[i * 4 + 3], w.w, s);
    }
    delta[g] = (s > 20.f) ? s : log1pf(expf(s));
}

// ---------------------------------------------------------------------------
// chunked selective scan, one thread per (b,c,d); 16 states in registers.
// ---------------------------------------------------------------------------
__global__ __launch_bounds__(256) void scan_a(const float* __restrict__ delta,
                                              const float* __restrict__ u,
                                              const float* __restrict__ x_dbl,
                                              const float* __restrict__ A_log,
                                              float* __restrict__ a_cum,
                                              float* __restrict__ h_end) {
    const int g = blockIdx.x * 256 + threadIdx.x;
    const int d = g & 511, bc = g >> 9;
    const int b = bc & 3, c = bc >> 2;

    float An[16];
    {
        const float4* ap = (const float4*)&A_log[d * 16];
#pragma unroll
        for (int q = 0; q < 4; ++q) {
            const float4 v = ap[q];
            An[q * 4 + 0] = -expf(v.x); An[q * 4 + 1] = -expf(v.y);
            An[q * 4 + 2] = -expf(v.z); An[q * 4 + 3] = -expf(v.w);
        }
    }
    float h[16];
#pragma unroll
    for (int n = 0; n < 16; ++n) h[n] = 0.f;
    float sumd = 0.f;

    const size_t row0 = (size_t)b * LL + (size_t)c * LC;
    float pd = delta[row0 * DINNER + d];
    float pu = u[row0 * DINNER + d];
    float4 pB[4];
    {
        const float4* bp = (const float4*)&x_dbl[row0 * NXP + DTRANK];
#pragma unroll
        for (int q = 0; q < 4; ++q) pB[q] = bp[q];
    }

    for (int i = 0; i < LC; ++i) {
        const float dlt = pd, uu = pu;
        float Bv[16] = {pB[0].x, pB[0].y, pB[0].z, pB[0].w,
                        pB[1].x, pB[1].y, pB[1].z, pB[1].w,
                        pB[2].x, pB[2].y, pB[2].z, pB[2].w,
                        pB[3].x, pB[3].y, pB[3].z, pB[3].w};
        if (i + 1 < LC) {  // wave-uniform branch
            const size_t row = row0 + i + 1;
            pd = delta[row * DINNER + d];
            pu = u[row * DINNER + d];
            const float4* bp = (const float4*)&x_dbl[row * NXP + DTRANK];
#pragma unroll
            for (int q = 0; q < 4; ++q) pB[q] = bp[q];
        }
        sumd += dlt;
        const float du = dlt * uu;
#pragma unroll
        for (int n = 0; n < 16; ++n)
            h[n] = fmaf(__expf(dlt * An[n]), h[n], du * Bv[n]);
    }

    const size_t o = ((size_t)(c * BB + b) * DINNER + d) * 16;
#pragma unroll
    for (int q = 0; q < 4; ++q) {
        *(float4*)&a_cum[o + q * 4] = make_float4(
            __expf(An[q * 4 + 0] * sumd), __expf(An[q * 4 + 1] * sumd),
            __expf(An[q * 4 + 2] * sumd), __expf(An[q * 4 + 3] * sumd));
        *(float4*)&h_end[o + q * 4] = make_float4(h[q * 4 + 0], h[q * 4 + 1],
                                                  h[q * 4 + 2], h[q * 4 + 3]);
    }
}

__global__ __launch_bounds__(256) void scan_b(const float* __restrict__ a_cum,
                                              const float* __restrict__ h_end,
                                              float* __restrict__ h_start) {
    const int g = blockIdx.x * 256 + threadIdx.x;  // BB*DINNER*DSTATE = 32768
    const int n = g & 15, d = (g >> 4) & 511, b = g >> 13;
    float hs = 0.f;
#pragma unroll 8
    for (int c = 0; c < NC; ++c) {
        const size_t idx = ((size_t)(c * BB + b) * DINNER + d) * 16 + n;
        h_start[idx] = hs;
        hs = fmaf(a_cum[idx], hs, h_end[idx]);
    }
}

__global__ __launch_bounds__(256) void scan_c(const float* __restrict__ delta,
                                              const float* __restrict__ u,
                                              const float* __restrict__ x_dbl,
                                              const float* __restrict__ A_log,
                                              const float* __restrict__ Dskip,
                                              const float* __restrict__ xz,
                                              const float* __restrict__ h_start,
                                              ushort* __restrict__ ygb) {
    const int g = blockIdx.x * 256 + threadIdx.x;
    const int d = g & 511, bc = g >> 9;
    const int b = bc & 3, c = bc >> 2;

    float An[16];
    {
        const float4* ap = (const float4*)&A_log[d * 16];
#pragma unroll
        for (int q = 0; q < 4; ++q) {
            const float4 v = ap[q];
            An[q * 4 + 0] = -expf(v.x); An[q * 4 + 1] = -expf(v.y);
            An[q * 4 + 2] = -expf(v.z); An[q * 4 + 3] = -expf(v.w);
        }
    }
    float h[16];
    {
        const size_t o = ((size_t)(c * BB + b) * DINNER + d) * 16;
#pragma unroll
        for (int q = 0; q < 4; ++q) {
            const float4 v = *(const float4*)&h_start[o + q * 4];
            h[q * 4 + 0] = v.x; h[q * 4 + 1] = v.y; h[q * 4 + 2] = v.z; h[q * 4 + 3] = v.w;
        }
    }
    const float dsk = Dskip[d];

    const size_t row0 = (size_t)b * LL + (size_t)c * LC;
    float pd = delta[row0 * DINNER + d];
    float pu = u[row0 * DINNER + d];
    float pz = xz[row0 * (2 * DINNER) + DINNER + d];
    float4 pB[4], pC[4];
    {
        const float4* bp = (const float4*)&x_dbl[row0 * NXP + DTRANK];
#pragma unroll
        for (int q = 0; q < 4; ++q) pB[q] = bp[q];
#pragma unroll
        for (int q = 0; q < 4; ++q) pC[q] = bp[4 + q];
    }

    for (int i = 0; i < LC; ++i) {
        const size_t crow = row0 + i;
        const float dlt = pd, uu = pu, zz = pz;
        float Bv[16] = {pB[0].x, pB[0].y, pB[0].z, pB[0].w,
                        pB[1].x, pB[1].y, pB[1].z, pB[1].w,
                        pB[2].x, pB[2].y, pB[2].z, pB[2].w,
                        pB[3].x, pB[3].y, pB[3].z, pB[3].w};
        float Cv[16] = {pC[0].x, pC[0].y, pC[0].z, pC[0].w,
                        pC[1].x, pC[1].y, pC[1].z, pC[1].w,
                        pC[2].x, pC[2].y, pC[2].z, pC[2].w,
                        pC[3].x, pC[3].y, pC[3].z, pC[3].w};
        if (i + 1 < LC) {  // wave-uniform branch
            const size_t row = crow + 1;
            pd = delta[row * DINNER + d];
            pu = u[row * DINNER + d];
            pz = xz[row * (2 * DINNER) + DINNER + d];
            const float4* bp = (const float4*)&x_dbl[row * NXP + DTRANK];
#pragma unroll
            for (int q = 0; q < 4; ++q) pB[q] = bp[q];
#pragma unroll
            for (int q = 0; q < 4; ++q) pC[q] = bp[4 + q];
        }
        const float du = dlt * uu;
#pragma unroll
        for (int n = 0; n < 16; ++n)
            h[n] = fmaf(__expf(dlt * An[n]), h[n], du * Bv[n]);
        float y = 0.f;
#pragma unroll
        for (int n = 0; n < 16; ++n) y = fmaf(h[n], Cv[n], y);
        y = fmaf(uu, dsk, y);
        const float sz = zz / (1.f + __expf(-zz));
        ygb[crow * DINNER + d] = f2bf(y * sz);
    }
}

// ---------------------------------------------------------------------------
extern "C" void kernel_launch(void* const* d_in, const int* in_sizes, int n_in,
                              void* d_out, int out_size, void* d_ws, size_t ws_size,
                              hipStream_t stream) {
    const float* x      = (const float*)d_in[0];
    const float* W_in   = (const float*)d_in[1];
    const float* conv_w = (const float*)d_in[2];
    const float* conv_b = (const float*)d_in[3];
    const float* W_xp   = (const float*)d_in[4];
    const float* W_dt   = (const float*)d_in[5];
    const float* b_dt   = (const float*)d_in[6];
    const float* A_log  = (const float*)d_in[7];
    const float* Dskip  = (const float*)d_in[8];
    const float* W_out  = (const float*)d_in[9];
    float* out = (float*)d_out;

    float* ws = (float*)d_ws;
    // fp32 regions (floats): total ~94.1 MB incl. bf16 aliases
    float* xz      = ws;                          // MROWS*1024  = 8.39M
    float* u       = xz + (size_t)MROWS * 1024;   // MROWS*512   = 4.19M
    float* x_dbl   = u + (size_t)MROWS * 512;     // MROWS*48    = 0.39M
    float* delta   = x_dbl + (size_t)MROWS * 48;  // MROWS*512   = 4.19M
    float* a_cum   = delta + (size_t)MROWS * 512; // 2.10M
    float* h_end   = a_cum + (size_t)NC * BB * 512 * 16;
    float* h_start = h_end + (size_t)NC * BB * 512 * 16;
    float* wob_f   = h_start + (size_t)NC * BB * 512 * 16;  // 65536 floats

    // bf16 aliases into regions that are dead at time of use:
    // xb, W_in_b, W_xp_b live inside `delta` (delta written at step 4, after use)
    ushort* xb     = (ushort*)delta;                          // MROWS*256 bf16
    ushort* W_in_b = (ushort*)(delta + 1048576);              // 1024*256
    ushort* W_xp_b = (ushort*)(delta + 1048576 + 131072);     // 48*512
    ushort* ub     = (ushort*)h_end;   // written step 2, read step 3; h_end written step 5
    ushort* ygb    = (ushort*)a_cum;   // written step 7 (a_cum dead after step 6), read step 8
    ushort* W_ou_b = (ushort*)wob_f;

    // 0) convert inputs/weights to bf16
    f2b4<<<(MROWS * DMODEL / 4 + 255) / 256, 256, 0, stream>>>(x, xb, MROWS * DMODEL / 4);
    f2b4<<<(1024 * DMODEL / 4 + 255) / 256, 256, 0, stream>>>(W_in, W_in_b, 1024 * DMODEL / 4);
    f2b4<<<(NXP * DINNER / 4 + 255) / 256, 256, 0, stream>>>(W_xp, W_xp_b, NXP * DINNER / 4);
    f2b4<<<(DMODEL * DINNER / 4 + 255) / 256, 256, 0, stream>>>(W_out, W_ou_b, DMODEL * DINNER / 4);

    // 1) in_proj: xz = x @ W_in^T   [8192,1024]
    {
        dim3 grid(1024 / 64, MROWS / 128);
        gemm_bf16_nt<0><<<grid, 256, 0, stream>>>(xb, W_in_b, xz, MROWS, 1024, DMODEL);
    }
    // 2) depthwise causal conv + SiLU -> u (f32 + bf16)
    conv_silu<<<(BB * LL * DINNER) / 256, 256, 0, stream>>>(xz, conv_w, conv_b, u, ub);
    // 3) x_proj: x_dbl = u @ W_xproj^T  [8192,48]
    {
        dim3 grid(1, MROWS / 128);
        gemm_bf16_nt<1><<<grid, 256, 0, stream>>>(ub, W_xp_b, x_dbl, MROWS, NXP, DINNER);
    }
    // 4) delta = softplus(dt @ W_dt^T + b_dt)
    dt_softplus<<<(MROWS * DINNER) / 256, 256, 0, stream>>>(x_dbl, W_dt, b_dt, delta);
    // 5-7) chunked selective scan + gating
    scan_a<<<(BB * NC * DINNER) / 256, 256, 0, stream>>>(delta, u, x_dbl, A_log, a_cum, h_end);
    scan_b<<<(BB * DINNER * DSTATE) / 256, 256, 0, stream>>>(a_cum, h_end, h_start);
    scan_c<<<(BB * NC * DINNER) / 256, 256, 0, stream>>>(delta, u, x_dbl, A_log, Dskip, xz,
                                                         h_start, ygb);
    // 8) out_proj: out = yg @ W_out^T  [8192,256]
    {
        dim3 grid(DMODEL / 64, MROWS / 128);
        gemm_bf16_nt<0><<<grid, 256, 0, stream>>>(ygb, W_ou_b, out, MROWS, DMODEL, DINNER);
    }
}

// Round 4
// 138.541 us; speedup vs baseline: 2.4461x; 1.2062x over previous
//
#include <hip/hip_runtime.h>
#include <hip/hip_bf16.h>
#include <math.h>

// Mamba block dims (fixed per reference)
#define BB 4
#define LL 2048
#define DMODEL 256
#define DINNER 512
#define DSTATE 16
#define DCONV 4
#define DTRANK 16
#define NXP 48            // DTRANK + 2*DSTATE
#define MROWS (BB*LL)     // 8192

// chunked scan config
#define NC 64
#define LC 32             // NC*LC == LL

typedef __attribute__((ext_vector_type(8))) short short8;   // 8 bf16 (4 VGPR)
typedef __attribute__((ext_vector_type(4))) float floatx4;  // MFMA accumulator

// round-to-nearest-even fp32 -> bf16 bits
static __device__ __forceinline__ ushort f2bf(float f) {
    unsigned u = __builtin_bit_cast(unsigned, f);
    unsigned r = (u + 0x7FFFu + ((u >> 16) & 1u)) >> 16;
    return (ushort)r;
}

// ---------------------------------------------------------------------------
// fp32 -> bf16 bulk convert (float4 in, ushort4 out)
// ---------------------------------------------------------------------------
__global__ __launch_bounds__(256) void f2b4(const float* __restrict__ s,
                                            ushort* __restrict__ d, int n4) {
    const int i = blockIdx.x * 256 + threadIdx.x;
    if (i < n4) {
        const float4 v = ((const float4*)s)[i];
        ushort4 o;
        o.x = f2bf(v.x); o.y = f2bf(v.y); o.z = f2bf(v.z); o.w = f2bf(v.w);
        ((ushort4*)d)[i] = o;
    }
}

// merged weight converts: W_in (65536 f4), W_xp (6144 f4), W_out (32768 f4)
__global__ __launch_bounds__(256) void w2b(const float* __restrict__ W_in,
                                           const float* __restrict__ W_xp,
                                           const float* __restrict__ W_out,
                                           ushort* __restrict__ o_in,
                                           ushort* __restrict__ o_xp,
                                           ushort* __restrict__ o_out) {
    const int i = blockIdx.x * 256 + threadIdx.x;  // 104448 total
    const float* s; ushort* d; int j;
    if (i < 65536)      { s = W_in;  d = o_in;  j = i; }
    else if (i < 71680) { s = W_xp;  d = o_xp;  j = i - 65536; }
    else                { s = W_out; d = o_out; j = i - 71680; }
    const float4 v = ((const float4*)s)[j];
    ushort4 o;
    o.x = f2bf(v.x); o.y = f2bf(v.y); o.z = f2bf(v.z); o.w = f2bf(v.w);
    ((ushort4*)d)[j] = o;
}

// ---------------------------------------------------------------------------
// bf16 MFMA GEMM, NT, LDS-staged: C[m,n] = sum_k A[m,k]*B[n,k]
// A[M,K], B[N,K] bf16, C[M,N] fp32. M % 128 == 0, K % 64 == 0.
// Block: 128x128 tile, 4 waves (2x2), wave tile 64x64 (4x4 MFMA 16x16x32).
// LDS: A/B tiles [128 rows][64 k] as 16B chunks, XOR-swizzled
//   chunk(r,kc) = r*8 + (kc ^ (r&7))   -> ds_read_b128/ds_write 2-way max.
// Reg-staged: next K-tile's global loads issued before the MFMA loop (T14).
// GUARDN=1: B rows/cols beyond N zero-filled / store-guarded (x_proj N=48).
// ---------------------------------------------------------------------------
template <int GUARDN>
__global__ __launch_bounds__(256) void gemm_bf16_lds(const ushort* __restrict__ A,
                                                     const ushort* __restrict__ Bw,
                                                     float* __restrict__ C,
                                                     int M, int N, int K) {
    __shared__ ushort As[8192];   // 16 KB
    __shared__ ushort Bs[8192];   // 16 KB
    const int tid = threadIdx.x;
    const int lane = tid & 63, wid = tid >> 6;
    const int wr = wid >> 1, wc = wid & 1;
    const int m0 = blockIdx.y * 128, n0 = blockIdx.x * 128;

    short8 ra[4], rb[4];
    const short8 z8 = {0, 0, 0, 0, 0, 0, 0, 0};

#define STAGE_LOAD(k0)                                                          \
    do {                                                                        \
        _Pragma("unroll") for (int i = 0; i < 4; ++i) {                         \
            const int c = tid + i * 256;                                        \
            const int r = c >> 3, kc = c & 7;                                   \
            ra[i] = *(const short8*)(A + (size_t)(m0 + r) * K + (k0) + kc * 8); \
            rb[i] = (GUARDN && (n0 + r) >= N)                                   \
                        ? z8                                                    \
                        : *(const short8*)(Bw + (size_t)(n0 + r) * K + (k0) + kc * 8); \
        }                                                                       \
    } while (0)

#define STAGE_WRITE()                                                           \
    do {                                                                        \
        _Pragma("unroll") for (int i = 0; i < 4; ++i) {                         \
            const int c = tid + i * 256;                                        \
            const int r = c >> 3, kc = c & 7;                                   \
            ((short8*)As)[r * 8 + (kc ^ (r & 7))] = ra[i];                      \
            ((short8*)Bs)[r * 8 + (kc ^ (r & 7))] = rb[i];                      \
        }                                                                       \
    } while (0)

    floatx4 acc[4][4];
#pragma unroll
    for (int i = 0; i < 4; ++i)
#pragma unroll
        for (int j = 0; j < 4; ++j) acc[i][j] = (floatx4){0.f, 0.f, 0.f, 0.f};

    const int nkt = K >> 6;
    const int rr = lane & 15, kh = lane >> 4;

    STAGE_LOAD(0);
    for (int t = 0; t < nkt; ++t) {
        __syncthreads();           // previous compute done before LDS overwrite
        STAGE_WRITE();
        __syncthreads();
        if (t + 1 < nkt) STAGE_LOAD((t + 1) * 64);  // overlaps MFMA below

#pragma unroll
        for (int kk = 0; kk < 2; ++kk) {
            const int kc = kk * 4 + kh;
            short8 af[4], bf[4];
#pragma unroll
            for (int ti = 0; ti < 4; ++ti) {
                const int r = wr * 64 + ti * 16 + rr;
                af[ti] = ((const short8*)As)[r * 8 + (kc ^ (r & 7))];
            }
#pragma unroll
            for (int tj = 0; tj < 4; ++tj) {
                const int r = wc * 64 + tj * 16 + rr;
                bf[tj] = ((const short8*)Bs)[r * 8 + (kc ^ (r & 7))];
            }
#pragma unroll
            for (int ti = 0; ti < 4; ++ti)
#pragma unroll
                for (int tj = 0; tj < 4; ++tj)
                    acc[ti][tj] = __builtin_amdgcn_mfma_f32_16x16x32_bf16(
                        af[ti], bf[tj], acc[ti][tj], 0, 0, 0);
        }
    }
#undef STAGE_LOAD
#undef STAGE_WRITE

    const int cr = (lane >> 4) * 4, cc = lane & 15;
#pragma unroll
    for (int ti = 0; ti < 4; ++ti)
#pragma unroll
        for (int tj = 0; tj < 4; ++tj) {
            const int col = n0 + wc * 64 + tj * 16 + cc;
            if (GUARDN && col >= N) continue;
#pragma unroll
            for (int j = 0; j < 4; ++j)
                C[(size_t)(m0 + wr * 64 + ti * 16 + cr + j) * N + col] = acc[ti][tj][j];
        }
}

// ---------------------------------------------------------------------------
// causal depthwise conv1d (k=4) + bias + SiLU; writes fp32 u and bf16 u
// ---------------------------------------------------------------------------
__global__ __launch_bounds__(256) void conv_silu(const float* __restrict__ xz,
                                                 const float* __restrict__ cw,
                                                 const float* __restrict__ cb,
                                                 float* __restrict__ u,
                                                 ushort* __restrict__ ub) {
    const int g = blockIdx.x * 256 + threadIdx.x;  // over BB*LL*DINNER
    const int d = g & (DINNER - 1);
    const int t = (g >> 9) & (LL - 1);
    const int b = g >> 20;
    const float w0 = cw[d * 4 + 0], w1 = cw[d * 4 + 1], w2 = cw[d * 4 + 2], w3 = cw[d * 4 + 3];
    const size_t base = ((size_t)(b * LL + t)) * (2 * DINNER) + d;
    float s = cb[d] + xz[base] * w3;
    if (t >= 1) s = fmaf(xz[base - 1024], w2, s);
    if (t >= 2) s = fmaf(xz[base - 2048], w1, s);
    if (t >= 3) s = fmaf(xz[base - 3072], w0, s);
    const float res = s / (1.f + expf(-s));
    u[g] = res;
    ub[g] = f2bf(res);
}

// ---------------------------------------------------------------------------
// delta = softplus(x_dbl[:, :16] @ W_dt^T + b_dt)
// ---------------------------------------------------------------------------
__global__ __launch_bounds__(256) void dt_softplus(const float* __restrict__ x_dbl,
                                                   const float* __restrict__ W_dt,
                                                   const float* __restrict__ b_dt,
                                                   float* __restrict__ delta) {
    const int g = blockIdx.x * 256 + threadIdx.x;  // over MROWS*DINNER
    const int d = g & (DINNER - 1);
    const int row = g >> 9;
    const float* xr = &x_dbl[(size_t)row * NXP];
    const float4* wr = (const float4*)&W_dt[d * DTRANK];
    float s = b_dt[d];
#pragma unroll
    for (int i = 0; i < 4; ++i) {
        const float4 w = wr[i];
        s = fmaf(xr[i * 4 + 0], w.x, s);
        s = fmaf(xr[i * 4 + 1], w.y, s);
        s = fmaf(xr[i * 4 + 2], w.z, s);
        s = fmaf(xr[i * 4 + 3], w.w, s);
    }
    delta[g] = (s > 20.f) ? s : log1pf(expf(s));
}

// ---------------------------------------------------------------------------
// chunked selective scan, one thread per (b,c,d); 16 states in registers.
// ---------------------------------------------------------------------------
__global__ __launch_bounds__(256) void scan_a(const float* __restrict__ delta,
                                              const float* __restrict__ u,
                                              const float* __restrict__ x_dbl,
                                              const float* __restrict__ A_log,
                                              float* __restrict__ a_cum,
                                              float* __restrict__ h_end) {
    const int g = blockIdx.x * 256 + threadIdx.x;
    const int d = g & 511, bc = g >> 9;
    const int b = bc & 3, c = bc >> 2;

    float An[16];
    {
        const float4* ap = (const float4*)&A_log[d * 16];
#pragma unroll
        for (int q = 0; q < 4; ++q) {
            const float4 v = ap[q];
            An[q * 4 + 0] = -expf(v.x); An[q * 4 + 1] = -expf(v.y);
            An[q * 4 + 2] = -expf(v.z); An[q * 4 + 3] = -expf(v.w);
        }
    }
    float h[16];
#pragma unroll
    for (int n = 0; n < 16; ++n) h[n] = 0.f;
    float sumd = 0.f;

    const size_t row0 = (size_t)b * LL + (size_t)c * LC;
    float pd = delta[row0 * DINNER + d];
    float pu = u[row0 * DINNER + d];
    float4 pB[4];
    {
        const float4* bp = (const float4*)&x_dbl[row0 * NXP + DTRANK];
#pragma unroll
        for (int q = 0; q < 4; ++q) pB[q] = bp[q];
    }

    for (int i = 0; i < LC; ++i) {
        const float dlt = pd, uu = pu;
        float Bv[16] = {pB[0].x, pB[0].y, pB[0].z, pB[0].w,
                        pB[1].x, pB[1].y, pB[1].z, pB[1].w,
                        pB[2].x, pB[2].y, pB[2].z, pB[2].w,
                        pB[3].x, pB[3].y, pB[3].z, pB[3].w};
        if (i + 1 < LC) {  // wave-uniform branch
            const size_t row = row0 + i + 1;
            pd = delta[row * DINNER + d];
            pu = u[row * DINNER + d];
            const float4* bp = (const float4*)&x_dbl[row * NXP + DTRANK];
#pragma unroll
            for (int q = 0; q < 4; ++q) pB[q] = bp[q];
        }
        sumd += dlt;
        const float du = dlt * uu;
#pragma unroll
        for (int n = 0; n < 16; ++n)
            h[n] = fmaf(__expf(dlt * An[n]), h[n], du * Bv[n]);
    }

    const size_t o = ((size_t)(c * BB + b) * DINNER + d) * 16;
#pragma unroll
    for (int q = 0; q < 4; ++q) {
        *(float4*)&a_cum[o + q * 4] = make_float4(
            __expf(An[q * 4 + 0] * sumd), __expf(An[q * 4 + 1] * sumd),
            __expf(An[q * 4 + 2] * sumd), __expf(An[q * 4 + 3] * sumd));
        *(float4*)&h_end[o + q * 4] = make_float4(h[q * 4 + 0], h[q * 4 + 1],
                                                  h[q * 4 + 2], h[q * 4 + 3]);
    }
}

__global__ __launch_bounds__(256) void scan_b(const float* __restrict__ a_cum,
                                              const float* __restrict__ h_end,
                                              float* __restrict__ h_start) {
    const int g = blockIdx.x * 256 + threadIdx.x;  // BB*DINNER*DSTATE = 32768
    const int n = g & 15, d = (g >> 4) & 511, b = g >> 13;
    float hs = 0.f;
#pragma unroll 8
    for (int c = 0; c < NC; ++c) {
        const size_t idx = ((size_t)(c * BB + b) * DINNER + d) * 16 + n;
        h_start[idx] = hs;
        hs = fmaf(a_cum[idx], hs, h_end[idx]);
    }
}

__global__ __launch_bounds__(256) void scan_c(const float* __restrict__ delta,
                                              const float* __restrict__ u,
                                              const float* __restrict__ x_dbl,
                                              const float* __restrict__ A_log,
                                              const float* __restrict__ Dskip,
                                              const float* __restrict__ xz,
                                              const float* __restrict__ h_start,
                                              ushort* __restrict__ ygb) {
    const int g = blockIdx.x * 256 + threadIdx.x;
    const int d = g & 511, bc = g >> 9;
    const int b = bc & 3, c = bc >> 2;

    float An[16];
    {
        const float4* ap = (const float4*)&A_log[d * 16];
#pragma unroll
        for (int q = 0; q < 4; ++q) {
            const float4 v = ap[q];
            An[q * 4 + 0] = -expf(v.x); An[q * 4 + 1] = -expf(v.y);
            An[q * 4 + 2] = -expf(v.z); An[q * 4 + 3] = -expf(v.w);
        }
    }
    float h[16];
    {
        const size_t o = ((size_t)(c * BB + b) * DINNER + d) * 16;
#pragma unroll
        for (int q = 0; q < 4; ++q) {
            const float4 v = *(const float4*)&h_start[o + q * 4];
            h[q * 4 + 0] = v.x; h[q * 4 + 1] = v.y; h[q * 4 + 2] = v.z; h[q * 4 + 3] = v.w;
        }
    }
    const float dsk = Dskip[d];

    const size_t row0 = (size_t)b * LL + (size_t)c * LC;
    float pd = delta[row0 * DINNER + d];
    float pu = u[row0 * DINNER + d];
    float pz = xz[row0 * (2 * DINNER) + DINNER + d];
    float4 pB[4], pC[4];
    {
        const float4* bp = (const float4*)&x_dbl[row0 * NXP + DTRANK];
#pragma unroll
        for (int q = 0; q < 4; ++q) pB[q] = bp[q];
#pragma unroll
        for (int q = 0; q < 4; ++q) pC[q] = bp[4 + q];
    }

    for (int i = 0; i < LC; ++i) {
        const size_t crow = row0 + i;
        const float dlt = pd, uu = pu, zz = pz;
        float Bv[16] = {pB[0].x, pB[0].y, pB[0].z, pB[0].w,
                        pB[1].x, pB[1].y, pB[1].z, pB[1].w,
                        pB[2].x, pB[2].y, pB[2].z, pB[2].w,
                        pB[3].x, pB[3].y, pB[3].z, pB[3].w};
        float Cv[16] = {pC[0].x, pC[0].y, pC[0].z, pC[0].w,
                        pC[1].x, pC[1].y, pC[1].z, pC[1].w,
                        pC[2].x, pC[2].y, pC[2].z, pC[2].w,
                        pC[3].x, pC[3].y, pC[3].z, pC[3].w};
        if (i + 1 < LC) {  // wave-uniform branch
            const size_t row = crow + 1;
            pd = delta[row * DINNER + d];
            pu = u[row * DINNER + d];
            pz = xz[row * (2 * DINNER) + DINNER + d];
            const float4* bp = (const float4*)&x_dbl[row * NXP + DTRANK];
#pragma unroll
            for (int q = 0; q < 4; ++q) pB[q] = bp[q];
#pragma unroll
            for (int q = 0; q < 4; ++q) pC[q] = bp[4 + q];
        }
        const float du = dlt * uu;
#pragma unroll
        for (int n = 0; n < 16; ++n)
            h[n] = fmaf(__expf(dlt * An[n]), h[n], du * Bv[n]);
        float y = 0.f;
#pragma unroll
        for (int n = 0; n < 16; ++n) y = fmaf(h[n], Cv[n], y);
        y = fmaf(uu, dsk, y);
        const float sz = zz / (1.f + __expf(-zz));
        ygb[crow * DINNER + d] = f2bf(y * sz);
    }
}

// ---------------------------------------------------------------------------
extern "C" void kernel_launch(void* const* d_in, const int* in_sizes, int n_in,
                              void* d_out, int out_size, void* d_ws, size_t ws_size,
                              hipStream_t stream) {
    const float* x      = (const float*)d_in[0];
    const float* W_in   = (const float*)d_in[1];
    const float* conv_w = (const float*)d_in[2];
    const float* conv_b = (const float*)d_in[3];
    const float* W_xp   = (const float*)d_in[4];
    const float* W_dt   = (const float*)d_in[5];
    const float* b_dt   = (const float*)d_in[6];
    const float* A_log  = (const float*)d_in[7];
    const float* Dskip  = (const float*)d_in[8];
    const float* W_out  = (const float*)d_in[9];
    float* out = (float*)d_out;

    float* ws = (float*)d_ws;
    // fp32 regions (floats): total ~94.1 MB incl. bf16 aliases
    float* xz      = ws;                          // MROWS*1024  = 8.39M
    float* u       = xz + (size_t)MROWS * 1024;   // MROWS*512   = 4.19M
    float* x_dbl   = u + (size_t)MROWS * 512;     // MROWS*48    = 0.39M
    float* delta   = x_dbl + (size_t)MROWS * 48;  // MROWS*512   = 4.19M
    float* a_cum   = delta + (size_t)MROWS * 512; // 2.10M
    float* h_end   = a_cum + (size_t)NC * BB * 512 * 16;
    float* h_start = h_end + (size_t)NC * BB * 512 * 16;
    float* wob_f   = h_start + (size_t)NC * BB * 512 * 16;  // 65536 floats

    // bf16 aliases into regions that are dead at time of use:
    // xb, W_in_b, W_xp_b live inside `delta` (delta written at step 4, after use)
    ushort* xb     = (ushort*)delta;                          // MROWS*256 bf16
    ushort* W_in_b = (ushort*)(delta + 1048576);              // 1024*256
    ushort* W_xp_b = (ushort*)(delta + 1048576 + 131072);     // 48*512
    ushort* ub     = (ushort*)h_end;   // written step 2, read step 3; h_end written step 5
    ushort* ygb    = (ushort*)a_cum;   // written step 7 (a_cum dead after step 6), read step 8
    ushort* W_ou_b = (ushort*)wob_f;

    // 0) convert inputs/weights to bf16
    f2b4<<<(MROWS * DMODEL / 4 + 255) / 256, 256, 0, stream>>>(x, xb, MROWS * DMODEL / 4);
    w2b<<<408, 256, 0, stream>>>(W_in, W_xp, W_out, W_in_b, W_xp_b, W_ou_b);

    // 1) in_proj: xz = x @ W_in^T   [8192,1024]
    {
        dim3 grid(1024 / 128, MROWS / 128);
        gemm_bf16_lds<0><<<grid, 256, 0, stream>>>(xb, W_in_b, xz, MROWS, 1024, DMODEL);
    }
    // 2) depthwise causal conv + SiLU -> u (f32 + bf16)
    conv_silu<<<(BB * LL * DINNER) / 256, 256, 0, stream>>>(xz, conv_w, conv_b, u, ub);
    // 3) x_proj: x_dbl = u @ W_xproj^T  [8192,48]
    {
        dim3 grid(1, MROWS / 128);
        gemm_bf16_lds<1><<<grid, 256, 0, stream>>>(ub, W_xp_b, x_dbl, MROWS, NXP, DINNER);
    }
    // 4) delta = softplus(dt @ W_dt^T + b_dt)
    dt_softplus<<<(MROWS * DINNER) / 256, 256, 0, stream>>>(x_dbl, W_dt, b_dt, delta);
    // 5-7) chunked selective scan + gating
    scan_a<<<(BB * NC * DINNER) / 256, 256, 0, stream>>>(delta, u, x_dbl, A_log, a_cum, h_end);
    scan_b<<<(BB * DINNER * DSTATE) / 256, 256, 0, stream>>>(a_cum, h_end, h_start);
    scan_c<<<(BB * NC * DINNER) / 256, 256, 0, stream>>>(delta, u, x_dbl, A_log, Dskip, xz,
                                                         h_start, ygb);
    // 8) out_proj: out = yg @ W_out^T  [8192,256]
    {
        dim3 grid(DMODEL / 128, MROWS / 128);
        gemm_bf16_lds<0><<<grid, 256, 0, stream>>>(ygb, W_ou_b, out, MROWS, DMODEL, DINNER);
    }
}

// Round 5
// 132.171 us; speedup vs baseline: 2.5640x; 1.0482x over previous
//
#include <hip/hip_runtime.h>
#include <hip/hip_bf16.h>
#include <math.h>

// Mamba block dims (fixed per reference)
#define BB 4
#define LL 2048
#define DMODEL 256
#define DINNER 512
#define DSTATE 16
#define DTRANK 16
#define NXP 48            // DTRANK + 2*DSTATE
#define MROWS (BB*LL)     // 8192

// chunked scan config
#define NC 64
#define LC 32             // NC*LC == LL

typedef __attribute__((ext_vector_type(8))) short short8;   // 8 bf16 (4 VGPR)
typedef __attribute__((ext_vector_type(4))) float floatx4;  // MFMA accumulator

// round-to-nearest-even fp32 -> bf16 bits
static __device__ __forceinline__ ushort f2bf(float f) {
    unsigned u = __builtin_bit_cast(unsigned, f);
    unsigned r = (u + 0x7FFFu + ((u >> 16) & 1u)) >> 16;
    return (ushort)r;
}
static __device__ __forceinline__ float bf2f(ushort h) {
    unsigned u = ((unsigned)h) << 16;
    return __builtin_bit_cast(float, u);
}
static __device__ __forceinline__ short8 cvt8(const float4 a, const float4 b) {
    short8 t;
    t[0] = (short)f2bf(a.x); t[1] = (short)f2bf(a.y);
    t[2] = (short)f2bf(a.z); t[3] = (short)f2bf(a.w);
    t[4] = (short)f2bf(b.x); t[5] = (short)f2bf(b.y);
    t[6] = (short)f2bf(b.z); t[7] = (short)f2bf(b.w);
    return t;
}

// ---------------------------------------------------------------------------
// merged weight converts: W_in (65536 f4), W_xp (6144 f4), W_out (32768 f4)
// ---------------------------------------------------------------------------
__global__ __launch_bounds__(256) void w2b(const float* __restrict__ W_in,
                                           const float* __restrict__ W_xp,
                                           const float* __restrict__ W_out,
                                           ushort* __restrict__ o_in,
                                           ushort* __restrict__ o_xp,
                                           ushort* __restrict__ o_out) {
    const int i = blockIdx.x * 256 + threadIdx.x;  // 104448 total
    const float* s; ushort* d; int j;
    if (i < 65536)      { s = W_in;  d = o_in;  j = i; }
    else if (i < 71680) { s = W_xp;  d = o_xp;  j = i - 65536; }
    else                { s = W_out; d = o_out; j = i - 71680; }
    const float4 v = ((const float4*)s)[j];
    ushort4 o;
    o.x = f2bf(v.x); o.y = f2bf(v.y); o.z = f2bf(v.z); o.w = f2bf(v.w);
    ((ushort4*)d)[j] = o;
}

// ---------------------------------------------------------------------------
// FUSED in_proj + depthwise causal conv1d + SiLU.
//   GEMM: xz = x @ W_in^T, tile 128x128, K=256. A = x fp32 (cvt in stage),
//   B = W_in bf16. Blocks bx<4 produce the u-half: conv+SiLU applied in the
//   epilogue (acc tile staged to LDS, 3-row halo recomputed in fp32),
//   emitting ub bf16. Blocks bx>=4 emit the z-half as zb bf16.
// LDS: union of GEMM stage buffers (32 KB, XOR-swizzled 16B chunks) and the
//   epilogue tile ut[67][132] fp32 (35.4 KB) -> dynamic 35376 B.
// ---------------------------------------------------------------------------
__global__ __launch_bounds__(256) void in_proj_conv(const float* __restrict__ x,
                                                    const ushort* __restrict__ Wb,
                                                    const float* __restrict__ Wf,
                                                    const float* __restrict__ cw,
                                                    const float* __restrict__ cb,
                                                    ushort* __restrict__ ub,
                                                    ushort* __restrict__ zb) {
    extern __shared__ char smem[];
    short8* As8 = (short8*)smem;           // [128 rows][8 kc] swizzled
    short8* Bs8 = As8 + 1024;
    float (*ut)[132] = (float(*)[132])smem;  // epilogue tile (rows: 3 halo + 64)

    const int tid = threadIdx.x;
    const int lane = tid & 63, wid = tid >> 6;
    const int wr = wid >> 1, wc = wid & 1;
    const int m0 = blockIdx.y * 128, n0 = blockIdx.x * 128;
    const bool is_u = (blockIdx.x < 4);
    const int K = DMODEL;  // 256

    floatx4 acc[4][4];
#pragma unroll
    for (int i = 0; i < 4; ++i)
#pragma unroll
        for (int j = 0; j < 4; ++j) acc[i][j] = (floatx4){0.f, 0.f, 0.f, 0.f};

    const int rr = lane & 15, kh = lane >> 4;
    short8 ra[4], rb[4];

#define STAGE_LOAD(k0)                                                          \
    do {                                                                        \
        _Pragma("unroll") for (int i = 0; i < 4; ++i) {                         \
            const int c = tid + i * 256;                                        \
            const int r = c >> 3, kc = c & 7;                                   \
            const float4* ap = (const float4*)&x[(size_t)(m0 + r) * K + (k0) + kc * 8]; \
            ra[i] = cvt8(ap[0], ap[1]);                                         \
            rb[i] = *(const short8*)(Wb + (size_t)(n0 + r) * K + (k0) + kc * 8); \
        }                                                                       \
    } while (0)

#define STAGE_WRITE()                                                           \
    do {                                                                        \
        _Pragma("unroll") for (int i = 0; i < 4; ++i) {                         \
            const int c = tid + i * 256;                                        \
            const int r = c >> 3, kc = c & 7;                                   \
            As8[r * 8 + (kc ^ (r & 7))] = ra[i];                                \
            Bs8[r * 8 + (kc ^ (r & 7))] = rb[i];                                \
        }                                                                       \
    } while (0)

    const int nkt = K >> 6;  // 4
    STAGE_LOAD(0);
    for (int t = 0; t < nkt; ++t) {
        __syncthreads();
        STAGE_WRITE();
        __syncthreads();
        if (t + 1 < nkt) STAGE_LOAD((t + 1) * 64);
#pragma unroll
        for (int kk = 0; kk < 2; ++kk) {
            const int kc = kk * 4 + kh;
            short8 af[4], bf[4];
#pragma unroll
            for (int ti = 0; ti < 4; ++ti) {
                const int r = wr * 64 + ti * 16 + rr;
                af[ti] = As8[r * 8 + (kc ^ (r & 7))];
            }
#pragma unroll
            for (int tj = 0; tj < 4; ++tj) {
                const int r = wc * 64 + tj * 16 + rr;
                bf[tj] = Bs8[r * 8 + (kc ^ (r & 7))];
            }
#pragma unroll
            for (int ti = 0; ti < 4; ++ti)
#pragma unroll
                for (int tj = 0; tj < 4; ++tj)
                    acc[ti][tj] = __builtin_amdgcn_mfma_f32_16x16x32_bf16(
                        af[ti], bf[tj], acc[ti][tj], 0, 0, 0);
        }
    }
#undef STAGE_LOAD
#undef STAGE_WRITE

    const int cr = (lane >> 4) * 4, cc = lane & 15;
    __syncthreads();  // MFMA LDS reads complete before union reuse / exit

    if (!is_u) {  // z-half: straight bf16 store
        const int zc0 = n0 - 512;
#pragma unroll
        for (int ti = 0; ti < 4; ++ti)
#pragma unroll
            for (int tj = 0; tj < 4; ++tj)
#pragma unroll
                for (int j = 0; j < 4; ++j)
                    zb[(size_t)(m0 + wr * 64 + ti * 16 + cr + j) * 512 +
                       zc0 + wc * 64 + tj * 16 + cc] = f2bf(acc[ti][tj][j]);
        return;
    }

    // ---- u-half epilogue: conv(k=4, causal) + bias + SiLU ----
    const int t0 = m0 & (LL - 1);
    // halo rows m0-3..m0-1 (pre-conv xz values), recomputed fp32; 0 at batch start
    float hval[2] = {0.f, 0.f};
    if (t0 != 0) {
#pragma unroll
        for (int p = 0; p < 2; ++p) {
            const int it = tid + p * 256;
            if (it < 384) {
                const int hr = it >> 7, hcol = it & 127;
                const float4* xr = (const float4*)&x[(size_t)(m0 - 3 + hr) * K];
                const float4* wv = (const float4*)&Wf[(size_t)(n0 + hcol) * K];
                float s = 0.f;
#pragma unroll 4
                for (int k = 0; k < 64; ++k) {
                    const float4 a = xr[k], w = wv[k];
                    s = fmaf(a.x, w.x, s); s = fmaf(a.y, w.y, s);
                    s = fmaf(a.z, w.z, s); s = fmaf(a.w, w.w, s);
                }
                hval[p] = s;
            }
        }
    }

    const int col = tid & 127, rowg = tid >> 7;   // conv work mapping
    const int d = n0 + col;
    const float w0 = cw[d * 4 + 0], w1 = cw[d * 4 + 1],
                w2 = cw[d * 4 + 2], w3 = cw[d * 4 + 3];
    const float cbv = cb[d];

    // pass 0: output rows m0 .. m0+63 (ut rows 3..66 = acc rows 0..63 of wr0)
#pragma unroll
    for (int p = 0; p < 2; ++p) {
        const int it = tid + p * 256;
        if (it < 384) ut[it >> 7][it & 127] = hval[p];
    }
    if (wr == 0)
#pragma unroll
        for (int ti = 0; ti < 4; ++ti)
#pragma unroll
            for (int tj = 0; tj < 4; ++tj)
#pragma unroll
                for (int j = 0; j < 4; ++j)
                    ut[3 + ti * 16 + cr + j][wc * 64 + tj * 16 + cc] = acc[ti][tj][j];
    __syncthreads();
#pragma unroll 4
    for (int q = 0; q < 32; ++q) {
        const int rl = rowg + q * 2;
        const float s = cbv + w0 * ut[rl][col] + w1 * ut[rl + 1][col] +
                        w2 * ut[rl + 2][col] + w3 * ut[rl + 3][col];
        ub[(size_t)(m0 + rl) * 512 + d] = f2bf(s / (1.f + __expf(-s)));
    }
    __syncthreads();
    // pass 1: rows m0+64 .. m0+127; halo rows 61..63 come from wr0 acc ti=3
    if (wr == 0 && (lane >> 4) == 3)
#pragma unroll
        for (int tj = 0; tj < 4; ++tj)
#pragma unroll
            for (int j = 1; j < 4; ++j)
                ut[j - 1][wc * 64 + tj * 16 + cc] = acc[3][tj][j];
    if (wr == 1)
#pragma unroll
        for (int ti = 0; ti < 4; ++ti)
#pragma unroll
            for (int tj = 0; tj < 4; ++tj)
#pragma unroll
                for (int j = 0; j < 4; ++j)
                    ut[3 + ti * 16 + cr + j][wc * 64 + tj * 16 + cc] = acc[ti][tj][j];
    __syncthreads();
#pragma unroll 4
    for (int q = 0; q < 32; ++q) {
        const int rl = rowg + q * 2;
        const float s = cbv + w0 * ut[rl][col] + w1 * ut[rl + 1][col] +
                        w2 * ut[rl + 2][col] + w3 * ut[rl + 3][col];
        ub[(size_t)(m0 + 64 + rl) * 512 + d] = f2bf(s / (1.f + __expf(-s)));
    }
}

// ---------------------------------------------------------------------------
// bf16 MFMA GEMM, NT, 64x128 tile (4 waves x [64x32]), LDS-staged+swizzled.
// A[M,K] bf16, B[N,K] bf16, C[M,N] fp32. M%64==0, K%64==0.
// GUARDN=1: B rows >= N zero-filled, C col stores guarded (x_proj N=48).
// ---------------------------------------------------------------------------
template <int GUARDN>
__global__ __launch_bounds__(256) void gemm64_bf16(const ushort* __restrict__ A,
                                                   const ushort* __restrict__ Bw,
                                                   float* __restrict__ C,
                                                   int M, int N, int K) {
    __shared__ ushort As[4096];   // 64x64 (8 KB)
    __shared__ ushort Bs[8192];   // 128x64 (16 KB)
    short8* As8 = (short8*)As;
    short8* Bs8 = (short8*)Bs;
    const int tid = threadIdx.x;
    const int lane = tid & 63, wid = tid >> 6;
    const int m0 = blockIdx.y * 64, n0 = blockIdx.x * 128;
    const int nw = wid * 32;
    const int rr = lane & 15, kh = lane >> 4;
    const short8 z8 = {0, 0, 0, 0, 0, 0, 0, 0};

    short8 ra[2], rb[4];
#define STAGE_LOAD(k0)                                                          \
    do {                                                                        \
        _Pragma("unroll") for (int i = 0; i < 2; ++i) {                         \
            const int c = tid + i * 256;                                        \
            const int r = c >> 3, kc = c & 7;                                   \
            ra[i] = *(const short8*)(A + (size_t)(m0 + r) * K + (k0) + kc * 8); \
        }                                                                       \
        _Pragma("unroll") for (int i = 0; i < 4; ++i) {                         \
            const int c = tid + i * 256;                                        \
            const int r = c >> 3, kc = c & 7;                                   \
            rb[i] = (GUARDN && (n0 + r) >= N)                                   \
                        ? z8                                                    \
                        : *(const short8*)(Bw + (size_t)(n0 + r) * K + (k0) + kc * 8); \
        }                                                                       \
    } while (0)

#define STAGE_WRITE()                                                           \
    do {                                                                        \
        _Pragma("unroll") for (int i = 0; i < 2; ++i) {                         \
            const int c = tid + i * 256;                                        \
            const int r = c >> 3, kc = c & 7;                                   \
            As8[r * 8 + (kc ^ (r & 7))] = ra[i];                                \
        }                                                                       \
        _Pragma("unroll") for (int i = 0; i < 4; ++i) {                         \
            const int c = tid + i * 256;                                        \
            const int r = c >> 3, kc = c & 7;                                   \
            Bs8[r * 8 + (kc ^ (r & 7))] = rb[i];                                \
        }                                                                       \
    } while (0)

    floatx4 acc[4][2];
#pragma unroll
    for (int i = 0; i < 4; ++i)
#pragma unroll
        for (int j = 0; j < 2; ++j) acc[i][j] = (floatx4){0.f, 0.f, 0.f, 0.f};

    const int nkt = K >> 6;
    STAGE_LOAD(0);
    for (int t = 0; t < nkt; ++t) {
        __syncthreads();
        STAGE_WRITE();
        __syncthreads();
        if (t + 1 < nkt) STAGE_LOAD((t + 1) * 64);
#pragma unroll
        for (int kk = 0; kk < 2; ++kk) {
            const int kc = kk * 4 + kh;
            short8 af[4], bf[2];
#pragma unroll
            for (int ti = 0; ti < 4; ++ti) {
                const int r = ti * 16 + rr;
                af[ti] = As8[r * 8 + (kc ^ (r & 7))];
            }
#pragma unroll
            for (int tj = 0; tj < 2; ++tj) {
                const int r = nw + tj * 16 + rr;
                bf[tj] = Bs8[r * 8 + (kc ^ (r & 7))];
            }
#pragma unroll
            for (int ti = 0; ti < 4; ++ti)
#pragma unroll
                for (int tj = 0; tj < 2; ++tj)
                    acc[ti][tj] = __builtin_amdgcn_mfma_f32_16x16x32_bf16(
                        af[ti], bf[tj], acc[ti][tj], 0, 0, 0);
        }
    }
#undef STAGE_LOAD
#undef STAGE_WRITE

    const int cr = (lane >> 4) * 4, cc = lane & 15;
#pragma unroll
    for (int ti = 0; ti < 4; ++ti)
#pragma unroll
        for (int tj = 0; tj < 2; ++tj) {
            const int colx = n0 + nw + tj * 16 + cc;
            if (GUARDN && colx >= N) continue;
#pragma unroll
            for (int j = 0; j < 4; ++j)
                C[(size_t)(m0 + ti * 16 + cr + j) * N + colx] = acc[ti][tj][j];
        }
}

// ---------------------------------------------------------------------------
// chunked selective scan, one thread per (b,c,d); 16 states in registers.
// dt_proj + softplus fused (W_dt row cached in VGPRs); u/z read as bf16.
// ---------------------------------------------------------------------------
__global__ __launch_bounds__(256) void scan_a(const ushort* __restrict__ ub,
                                              const float* __restrict__ x_dbl,
                                              const float* __restrict__ A_log,
                                              const float* __restrict__ W_dt,
                                              const float* __restrict__ b_dt,
                                              float* __restrict__ a_cum,
                                              float* __restrict__ h_end) {
    const int g = blockIdx.x * 256 + threadIdx.x;
    const int d = g & 511, bc = g >> 9;
    const int b = bc & 3, c = bc >> 2;

    float An[16], Wd[16];
    {
        const float4* ap = (const float4*)&A_log[d * 16];
        const float4* wp = (const float4*)&W_dt[d * 16];
#pragma unroll
        for (int q = 0; q < 4; ++q) {
            const float4 v = ap[q];
            An[q * 4 + 0] = -expf(v.x); An[q * 4 + 1] = -expf(v.y);
            An[q * 4 + 2] = -expf(v.z); An[q * 4 + 3] = -expf(v.w);
            const float4 w = wp[q];
            Wd[q * 4 + 0] = w.x; Wd[q * 4 + 1] = w.y;
            Wd[q * 4 + 2] = w.z; Wd[q * 4 + 3] = w.w;
        }
    }
    const float bd = b_dt[d];
    float h[16];
#pragma unroll
    for (int n = 0; n < 16; ++n) h[n] = 0.f;
    float sumd = 0.f;

    const size_t row0 = (size_t)b * LL + (size_t)c * LC;
    ushort pu = ub[row0 * 512 + d];
    float4 pD[4], pB[4];
    {
        const float4* xp = (const float4*)&x_dbl[row0 * NXP];
#pragma unroll
        for (int q = 0; q < 4; ++q) { pD[q] = xp[q]; pB[q] = xp[4 + q]; }
    }

    for (int i = 0; i < LC; ++i) {
        const float uu = bf2f(pu);
        float Dv[16] = {pD[0].x, pD[0].y, pD[0].z, pD[0].w,
                        pD[1].x, pD[1].y, pD[1].z, pD[1].w,
                        pD[2].x, pD[2].y, pD[2].z, pD[2].w,
                        pD[3].x, pD[3].y, pD[3].z, pD[3].w};
        float Bv[16] = {pB[0].x, pB[0].y, pB[0].z, pB[0].w,
                        pB[1].x, pB[1].y, pB[1].z, pB[1].w,
                        pB[2].x, pB[2].y, pB[2].z, pB[2].w,
                        pB[3].x, pB[3].y, pB[3].z, pB[3].w};
        if (i + 1 < LC) {  // wave-uniform branch
            const size_t row = row0 + i + 1;
            pu = ub[row * 512 + d];
            const float4* xp = (const float4*)&x_dbl[row * NXP];
#pragma unroll
            for (int q = 0; q < 4; ++q) { pD[q] = xp[q]; pB[q] = xp[4 + q]; }
        }
        float s = bd;
#pragma unroll
        for (int n = 0; n < 16; ++n) s = fmaf(Dv[n], Wd[n], s);
        const float dlt = (s > 20.f) ? s : __logf(1.f + __expf(s));
        sumd += dlt;
        const float du = dlt * uu;
#pragma unroll
        for (int n = 0; n < 16; ++n)
            h[n] = fmaf(__expf(dlt * An[n]), h[n], du * Bv[n]);
    }

    const size_t o = ((size_t)(c * BB + b) * DINNER + d) * 16;
#pragma unroll
    for (int q = 0; q < 4; ++q) {
        *(float4*)&a_cum[o + q * 4] = make_float4(
            __expf(An[q * 4 + 0] * sumd), __expf(An[q * 4 + 1] * sumd),
            __expf(An[q * 4 + 2] * sumd), __expf(An[q * 4 + 3] * sumd));
        *(float4*)&h_end[o + q * 4] = make_float4(h[q * 4 + 0], h[q * 4 + 1],
                                                  h[q * 4 + 2], h[q * 4 + 3]);
    }
}

__global__ __launch_bounds__(256) void scan_b(const float* __restrict__ a_cum,
                                              const float* __restrict__ h_end,
                                              float* __restrict__ h_start) {
    const int g = blockIdx.x * 256 + threadIdx.x;  // BB*DINNER*DSTATE = 32768
    const int n = g & 15, d = (g >> 4) & 511, b = g >> 13;
    float hs = 0.f;
#pragma unroll 8
    for (int c = 0; c < NC; ++c) {
        const size_t idx = ((size_t)(c * BB + b) * DINNER + d) * 16 + n;
        h_start[idx] = hs;
        hs = fmaf(a_cum[idx], hs, h_end[idx]);
    }
}

__global__ __launch_bounds__(256) void scan_c(const ushort* __restrict__ ub,
                                              const ushort* __restrict__ zb,
                                              const float* __restrict__ x_dbl,
                                              const float* __restrict__ A_log,
                                              const float* __restrict__ W_dt,
                                              const float* __restrict__ b_dt,
                                              const float* __restrict__ Dskip,
                                              const float* __restrict__ h_start,
                                              ushort* __restrict__ ygb) {
    const int g = blockIdx.x * 256 + threadIdx.x;
    const int d = g & 511, bc = g >> 9;
    const int b = bc & 3, c = bc >> 2;

    float An[16], Wd[16];
    {
        const float4* ap = (const float4*)&A_log[d * 16];
        const float4* wp = (const float4*)&W_dt[d * 16];
#pragma unroll
        for (int q = 0; q < 4; ++q) {
            const float4 v = ap[q];
            An[q * 4 + 0] = -expf(v.x); An[q * 4 + 1] = -expf(v.y);
            An[q * 4 + 2] = -expf(v.z); An[q * 4 + 3] = -expf(v.w);
            const float4 w = wp[q];
            Wd[q * 4 + 0] = w.x; Wd[q * 4 + 1] = w.y;
            Wd[q * 4 + 2] = w.z; Wd[q * 4 + 3] = w.w;
        }
    }
    const float bd = b_dt[d];
    float h[16];
    {
        const size_t o = ((size_t)(c * BB + b) * DINNER + d) * 16;
#pragma unroll
        for (int q = 0; q < 4; ++q) {
            const float4 v = *(const float4*)&h_start[o + q * 4];
            h[q * 4 + 0] = v.x; h[q * 4 + 1] = v.y;
            h[q * 4 + 2] = v.z; h[q * 4 + 3] = v.w;
        }
    }
    const float dsk = Dskip[d];

    const size_t row0 = (size_t)b * LL + (size_t)c * LC;
    ushort pu = ub[row0 * 512 + d];
    ushort pz = zb[row0 * 512 + d];
    float4 pD[4], pB[4], pC[4];
    {
        const float4* xp = (const float4*)&x_dbl[row0 * NXP];
#pragma unroll
        for (int q = 0; q < 4; ++q) { pD[q] = xp[q]; pB[q] = xp[4 + q]; pC[q] = xp[8 + q]; }
    }

    for (int i = 0; i < LC; ++i) {
        const size_t crow = row0 + i;
        const float uu = bf2f(pu), zz = bf2f(pz);
        float Dv[16] = {pD[0].x, pD[0].y, pD[0].z, pD[0].w,
                        pD[1].x, pD[1].y, pD[1].z, pD[1].w,
                        pD[2].x, pD[2].y, pD[2].z, pD[2].w,
                        pD[3].x, pD[3].y, pD[3].z, pD[3].w};
        float Bv[16] = {pB[0].x, pB[0].y, pB[0].z, pB[0].w,
                        pB[1].x, pB[1].y, pB[1].z, pB[1].w,
                        pB[2].x, pB[2].y, pB[2].z, pB[2].w,
                        pB[3].x, pB[3].y, pB[3].z, pB[3].w};
        float Cv[16] = {pC[0].x, pC[0].y, pC[0].z, pC[0].w,
                        pC[1].x, pC[1].y, pC[1].z, pC[1].w,
                        pC[2].x, pC[2].y, pC[2].z, pC[2].w,
                        pC[3].x, pC[3].y, pC[3].z, pC[3].w};
        if (i + 1 < LC) {  // wave-uniform branch
            const size_t row = crow + 1;
            pu = ub[row * 512 + d];
            pz = zb[row * 512 + d];
            const float4* xp = (const float4*)&x_dbl[row * NXP];
#pragma unroll
            for (int q = 0; q < 4; ++q) { pD[q] = xp[q]; pB[q] = xp[4 + q]; pC[q] = xp[8 + q]; }
        }
        float s = bd;
#pragma unroll
        for (int n = 0; n < 16; ++n) s = fmaf(Dv[n], Wd[n], s);
        const float dlt = (s > 20.f) ? s : __logf(1.f + __expf(s));
        const float du = dlt * uu;
#pragma unroll
        for (int n = 0; n < 16; ++n)
            h[n] = fmaf(__expf(dlt * An[n]), h[n], du * Bv[n]);
        float y = 0.f;
#pragma unroll
        for (int n = 0; n < 16; ++n) y = fmaf(h[n], Cv[n], y);
        y = fmaf(uu, dsk, y);
        const float sz = zz / (1.f + __expf(-zz));
        ygb[crow * 512 + d] = f2bf(y * sz);
    }
}

// ---------------------------------------------------------------------------
extern "C" void kernel_launch(void* const* d_in, const int* in_sizes, int n_in,
                              void* d_out, int out_size, void* d_ws, size_t ws_size,
                              hipStream_t stream) {
    const float* x      = (const float*)d_in[0];
    const float* W_in   = (const float*)d_in[1];
    const float* conv_w = (const float*)d_in[2];
    const float* conv_b = (const float*)d_in[3];
    const float* W_xp   = (const float*)d_in[4];
    const float* W_dt   = (const float*)d_in[5];
    const float* b_dt   = (const float*)d_in[6];
    const float* A_log  = (const float*)d_in[7];
    const float* Dskip  = (const float*)d_in[8];
    const float* W_out  = (const float*)d_in[9];
    float* out = (float*)d_out;

    // workspace layout (~53 MB, no aliasing)
    ushort* ub     = (ushort*)d_ws;                 // 8192*512 bf16
    ushort* zb     = ub + (size_t)MROWS * 512;
    ushort* ygb    = zb + (size_t)MROWS * 512;
    ushort* W_in_b = ygb + (size_t)MROWS * 512;     // 1024*256
    ushort* W_xp_b = W_in_b + 1024 * 256;           // 48*512
    ushort* W_ou_b = W_xp_b + 48 * 512;             // 256*512
    float* x_dbl   = (float*)(W_ou_b + 256 * 512);  // 8192*48
    float* a_cum   = x_dbl + (size_t)MROWS * NXP;   // 2.1M each
    float* h_end   = a_cum + (size_t)NC * BB * DINNER * DSTATE;
    float* h_start = h_end + (size_t)NC * BB * DINNER * DSTATE;

    // 0) weights -> bf16
    w2b<<<408, 256, 0, stream>>>(W_in, W_xp, W_out, W_in_b, W_xp_b, W_ou_b);

    // 1) fused in_proj + conv + SiLU -> ub (bf16), zb (bf16)
    {
        dim3 grid(8, MROWS / 128);
        in_proj_conv<<<grid, 256, 35376, stream>>>(x, W_in_b, W_in, conv_w, conv_b, ub, zb);
    }
    // 2) x_proj: x_dbl = u @ W_xproj^T  [8192,48]
    {
        dim3 grid(1, MROWS / 64);
        gemm64_bf16<1><<<grid, 256, 0, stream>>>(ub, W_xp_b, x_dbl, MROWS, NXP, DINNER);
    }
    // 3-5) chunked selective scan (dt_proj+softplus fused) + gating
    scan_a<<<(BB * NC * DINNER) / 256, 256, 0, stream>>>(ub, x_dbl, A_log, W_dt, b_dt,
                                                         a_cum, h_end);
    scan_b<<<(BB * DINNER * DSTATE) / 256, 256, 0, stream>>>(a_cum, h_end, h_start);
    scan_c<<<(BB * NC * DINNER) / 256, 256, 0, stream>>>(ub, zb, x_dbl, A_log, W_dt, b_dt,
                                                         Dskip, h_start, ygb);
    // 6) out_proj: out = yg @ W_out^T  [8192,256]
    {
        dim3 grid(DMODEL / 128, MROWS / 64);
        gemm64_bf16<0><<<grid, 256, 0, stream>>>(ygb, W_ou_b, out, MROWS, DMODEL, DINNER);
    }
}

// Round 6
// 113.735 us; speedup vs baseline: 2.9796x; 1.1621x over previous
//
#include <hip/hip_runtime.h>
#include <hip/hip_bf16.h>
#include <math.h>

// Mamba block dims (fixed per reference)
#define BB 4
#define LL 2048
#define DMODEL 256
#define DINNER 512
#define DSTATE 16
#define DTRANK 16
#define NXP 48            // DTRANK + 2*DSTATE
#define MROWS (BB*LL)     // 8192

// chunked scan config
#define NC 64
#define LC 32             // NC*LC == LL

typedef __attribute__((ext_vector_type(8))) short short8;   // 8 bf16 (4 VGPR)
typedef __attribute__((ext_vector_type(4))) float floatx4;  // MFMA accumulator

// round-to-nearest-even fp32 -> bf16 bits
static __device__ __forceinline__ ushort f2bf(float f) {
    unsigned u = __builtin_bit_cast(unsigned, f);
    unsigned r = (u + 0x7FFFu + ((u >> 16) & 1u)) >> 16;
    return (ushort)r;
}
static __device__ __forceinline__ float bf2f(ushort h) {
    unsigned u = ((unsigned)h) << 16;
    return __builtin_bit_cast(float, u);
}

// ---------------------------------------------------------------------------
// bulk fp32 -> bf16: x (524288 f4), W_in (65536), W_xp (6144), W_out (32768)
// ---------------------------------------------------------------------------
__global__ __launch_bounds__(256) void cvt_all(const float* __restrict__ x,
                                               const float* __restrict__ W_in,
                                               const float* __restrict__ W_xp,
                                               const float* __restrict__ W_out,
                                               ushort* __restrict__ ox,
                                               ushort* __restrict__ o_in,
                                               ushort* __restrict__ o_xp,
                                               ushort* __restrict__ o_out) {
    const int i = blockIdx.x * 256 + threadIdx.x;  // 628736 total
    const float* s; ushort* d; int j;
    if (i < 524288)      { s = x;     d = ox;    j = i; }
    else if (i < 589824) { s = W_in;  d = o_in;  j = i - 524288; }
    else if (i < 595968) { s = W_xp;  d = o_xp;  j = i - 589824; }
    else                 { s = W_out; d = o_out; j = i - 595968; }
    const float4 v = ((const float4*)s)[j];
    ushort4 o;
    o.x = f2bf(v.x); o.y = f2bf(v.y); o.z = f2bf(v.z); o.w = f2bf(v.w);
    ((ushort4*)d)[j] = o;
}

// ---------------------------------------------------------------------------
// Shared GEMM core: 64x64 tile, 4 waves (2x2), wave 32x32 (2x2 MFMA frags),
// LDS 2x8KB XOR-swizzled. NT layout, K % 64 == 0.
// ---------------------------------------------------------------------------
#define GEMM64_CORE(GUARDN)                                                     \
    short8* As8 = (short8*)As;                                                  \
    short8* Bs8 = (short8*)Bs;                                                  \
    const int tid = threadIdx.x;                                                \
    const int lane = tid & 63, wid = tid >> 6;                                  \
    const int wr = wid >> 1, wc = wid & 1;                                      \
    const int m0 = blockIdx.y * 64, n0 = blockIdx.x * 64;                       \
    const int rr = lane & 15, kh = lane >> 4;                                   \
    const short8 z8 = {0, 0, 0, 0, 0, 0, 0, 0};                                 \
    (void)z8;                                                                   \
    short8 ra[2], rb[2];                                                        \
    floatx4 acc[2][2];                                                          \
    _Pragma("unroll") for (int i = 0; i < 2; ++i)                               \
        _Pragma("unroll") for (int j = 0; j < 2; ++j)                           \
            acc[i][j] = (floatx4){0.f, 0.f, 0.f, 0.f};                          \
    const int nkt = K >> 6;                                                     \
    STAGE_LOAD(0);                                                              \
    for (int t = 0; t < nkt; ++t) {                                             \
        __syncthreads();                                                        \
        _Pragma("unroll") for (int i = 0; i < 2; ++i) {                         \
            const int c = tid + i * 256;                                        \
            const int r = c >> 3, kc = c & 7;                                   \
            As8[r * 8 + (kc ^ (r & 7))] = ra[i];                                \
            Bs8[r * 8 + (kc ^ (r & 7))] = rb[i];                                \
        }                                                                       \
        __syncthreads();                                                        \
        if (t + 1 < nkt) STAGE_LOAD((t + 1) * 64);                              \
        _Pragma("unroll") for (int kk = 0; kk < 2; ++kk) {                      \
            const int kc = kk * 4 + kh;                                         \
            short8 af[2], bf[2];                                                \
            _Pragma("unroll") for (int ti = 0; ti < 2; ++ti) {                  \
                const int r = wr * 32 + ti * 16 + rr;                           \
                af[ti] = As8[r * 8 + (kc ^ (r & 7))];                           \
            }                                                                   \
            _Pragma("unroll") for (int tj = 0; tj < 2; ++tj) {                  \
                const int r = wc * 32 + tj * 16 + rr;                           \
                bf[tj] = Bs8[r * 8 + (kc ^ (r & 7))];                           \
            }                                                                   \
            _Pragma("unroll") for (int ti = 0; ti < 2; ++ti)                    \
                _Pragma("unroll") for (int tj = 0; tj < 2; ++tj)                \
                    acc[ti][tj] = __builtin_amdgcn_mfma_f32_16x16x32_bf16(      \
                        af[ti], bf[tj], acc[ti][tj], 0, 0, 0);                  \
        }                                                                       \
    }                                                                           \
    const int cr = (lane >> 4) * 4, cc = lane & 15;

// ---------------------------------------------------------------------------
// in_proj: xz = x @ W_in^T, N=1024 split: bx<8 -> xu fp32, bx>=8 -> zb bf16
// grid (16, 128) = 2048 blocks
// ---------------------------------------------------------------------------
__global__ __launch_bounds__(256) void in_gemm64(const ushort* __restrict__ A,
                                                 const ushort* __restrict__ Bw,
                                                 float* __restrict__ xu,
                                                 ushort* __restrict__ zb) {
    const int K = DMODEL;
    __shared__ ushort As[4096], Bs[4096];
#define STAGE_LOAD(k0)                                                          \
    do {                                                                        \
        _Pragma("unroll") for (int i = 0; i < 2; ++i) {                         \
            const int c = tid + i * 256;                                        \
            const int r = c >> 3, kc = c & 7;                                   \
            ra[i] = *(const short8*)(A + (size_t)(m0 + r) * K + (k0) + kc * 8); \
            rb[i] = *(const short8*)(Bw + (size_t)(n0 + r) * K + (k0) + kc * 8);\
        }                                                                       \
    } while (0)
    GEMM64_CORE(0)
#undef STAGE_LOAD
    if (blockIdx.x < 8) {
#pragma unroll
        for (int ti = 0; ti < 2; ++ti)
#pragma unroll
            for (int tj = 0; tj < 2; ++tj)
#pragma unroll
                for (int j = 0; j < 4; ++j)
                    xu[(size_t)(m0 + wr * 32 + ti * 16 + cr + j) * 512 +
                       n0 + wc * 32 + tj * 16 + cc] = acc[ti][tj][j];
    } else {
        const int zc0 = n0 - 512;
#pragma unroll
        for (int ti = 0; ti < 2; ++ti)
#pragma unroll
            for (int tj = 0; tj < 2; ++tj)
#pragma unroll
                for (int j = 0; j < 4; ++j)
                    zb[(size_t)(m0 + wr * 32 + ti * 16 + cr + j) * 512 +
                       zc0 + wc * 32 + tj * 16 + cc] = f2bf(acc[ti][tj][j]);
    }
}

// ---------------------------------------------------------------------------
// generic NT GEMM 64x64, C fp32. GUARDN=1: N-ragged (x_proj N=48).
// ---------------------------------------------------------------------------
template <int GUARDN>
__global__ __launch_bounds__(256) void gemm_nt64(const ushort* __restrict__ A,
                                                 const ushort* __restrict__ Bw,
                                                 float* __restrict__ C,
                                                 int M, int N, int K) {
    __shared__ ushort As[4096], Bs[4096];
#define STAGE_LOAD(k0)                                                          \
    do {                                                                        \
        _Pragma("unroll") for (int i = 0; i < 2; ++i) {                         \
            const int c = tid + i * 256;                                        \
            const int r = c >> 3, kc = c & 7;                                   \
            ra[i] = *(const short8*)(A + (size_t)(m0 + r) * K + (k0) + kc * 8); \
            rb[i] = (GUARDN && (n0 + r) >= N)                                   \
                        ? z8                                                    \
                        : *(const short8*)(Bw + (size_t)(n0 + r) * K + (k0) + kc * 8); \
        }                                                                       \
    } while (0)
    GEMM64_CORE(GUARDN)
#undef STAGE_LOAD
#pragma unroll
    for (int ti = 0; ti < 2; ++ti)
#pragma unroll
        for (int tj = 0; tj < 2; ++tj) {
            const int colx = n0 + wc * 32 + tj * 16 + cc;
            if (GUARDN && colx >= N) continue;
#pragma unroll
            for (int j = 0; j < 4; ++j)
                C[(size_t)(m0 + wr * 32 + ti * 16 + cr + j) * N + colx] = acc[ti][tj][j];
        }
}

// ---------------------------------------------------------------------------
// causal depthwise conv1d (k=4) + bias + SiLU: xu fp32 -> ub bf16
// one thread per (row, 8 channels); grid 2048 blocks
// ---------------------------------------------------------------------------
__global__ __launch_bounds__(256) void conv_silu(const float* __restrict__ xu,
                                                 const float* __restrict__ cw,
                                                 const float* __restrict__ cb,
                                                 ushort* __restrict__ ub) {
    const int g = blockIdx.x * 256 + threadIdx.x;   // MROWS*64
    const int d0 = (g & 63) * 8;
    const int row = g >> 6;
    const int t = row & (LL - 1);
    const float* base = xu + (size_t)row * 512 + d0;
    float r0[8], r1[8] = {0}, r2[8] = {0}, r3[8] = {0};
    *(float4*)&r0[0] = *(const float4*)base;
    *(float4*)&r0[4] = *(const float4*)(base + 4);
    if (t >= 1) { *(float4*)&r1[0] = *(const float4*)(base - 512);
                  *(float4*)&r1[4] = *(const float4*)(base - 508); }
    if (t >= 2) { *(float4*)&r2[0] = *(const float4*)(base - 1024);
                  *(float4*)&r2[4] = *(const float4*)(base - 1020); }
    if (t >= 3) { *(float4*)&r3[0] = *(const float4*)(base - 1536);
                  *(float4*)&r3[4] = *(const float4*)(base - 1532); }
    short8 o;
#pragma unroll
    for (int e = 0; e < 8; ++e) {
        const int d = d0 + e;
        const float4 w = *(const float4*)&cw[d * 4];
        float s = cb[d];
        s = fmaf(w.w, r0[e], s);
        s = fmaf(w.z, r1[e], s);
        s = fmaf(w.y, r2[e], s);
        s = fmaf(w.x, r3[e], s);
        o[e] = (short)f2bf(s / (1.f + __expf(-s)));
    }
    *(short8*)&ub[(size_t)row * 512 + d0] = o;
}

// ---------------------------------------------------------------------------
// chunked selective scan, one thread per (b,c,d); 16 states in registers.
// dt_proj + softplus fused (W_dt row cached in VGPRs); u/z read as bf16.
// ---------------------------------------------------------------------------
__global__ __launch_bounds__(256) void scan_a(const ushort* __restrict__ ub,
                                              const float* __restrict__ x_dbl,
                                              const float* __restrict__ A_log,
                                              const float* __restrict__ W_dt,
                                              const float* __restrict__ b_dt,
                                              float* __restrict__ a_cum,
                                              float* __restrict__ h_end) {
    const int g = blockIdx.x * 256 + threadIdx.x;
    const int d = g & 511, bc = g >> 9;
    const int b = bc & 3, c = bc >> 2;

    float An[16], Wd[16];
    {
        const float4* ap = (const float4*)&A_log[d * 16];
        const float4* wp = (const float4*)&W_dt[d * 16];
#pragma unroll
        for (int q = 0; q < 4; ++q) {
            const float4 v = ap[q];
            An[q * 4 + 0] = -expf(v.x); An[q * 4 + 1] = -expf(v.y);
            An[q * 4 + 2] = -expf(v.z); An[q * 4 + 3] = -expf(v.w);
            const float4 w = wp[q];
            Wd[q * 4 + 0] = w.x; Wd[q * 4 + 1] = w.y;
            Wd[q * 4 + 2] = w.z; Wd[q * 4 + 3] = w.w;
        }
    }
    const float bd = b_dt[d];
    float h[16];
#pragma unroll
    for (int n = 0; n < 16; ++n) h[n] = 0.f;
    float sumd = 0.f;

    const size_t row0 = (size_t)b * LL + (size_t)c * LC;
    ushort pu = ub[row0 * 512 + d];
    float4 pD[4], pB[4];
    {
        const float4* xp = (const float4*)&x_dbl[row0 * NXP];
#pragma unroll
        for (int q = 0; q < 4; ++q) { pD[q] = xp[q]; pB[q] = xp[4 + q]; }
    }

    for (int i = 0; i < LC; ++i) {
        const float uu = bf2f(pu);
        float Dv[16] = {pD[0].x, pD[0].y, pD[0].z, pD[0].w,
                        pD[1].x, pD[1].y, pD[1].z, pD[1].w,
                        pD[2].x, pD[2].y, pD[2].z, pD[2].w,
                        pD[3].x, pD[3].y, pD[3].z, pD[3].w};
        float Bv[16] = {pB[0].x, pB[0].y, pB[0].z, pB[0].w,
                        pB[1].x, pB[1].y, pB[1].z, pB[1].w,
                        pB[2].x, pB[2].y, pB[2].z, pB[2].w,
                        pB[3].x, pB[3].y, pB[3].z, pB[3].w};
        if (i + 1 < LC) {  // wave-uniform branch
            const size_t row = row0 + i + 1;
            pu = ub[row * 512 + d];
            const float4* xp = (const float4*)&x_dbl[row * NXP];
#pragma unroll
            for (int q = 0; q < 4; ++q) { pD[q] = xp[q]; pB[q] = xp[4 + q]; }
        }
        float s = bd;
#pragma unroll
        for (int n = 0; n < 16; ++n) s = fmaf(Dv[n], Wd[n], s);
        const float dlt = (s > 20.f) ? s : __logf(1.f + __expf(s));
        sumd += dlt;
        const float du = dlt * uu;
#pragma unroll
        for (int n = 0; n < 16; ++n)
            h[n] = fmaf(__expf(dlt * An[n]), h[n], du * Bv[n]);
    }

    const size_t o = ((size_t)(c * BB + b) * DINNER + d) * 16;
#pragma unroll
    for (int q = 0; q < 4; ++q) {
        *(float4*)&a_cum[o + q * 4] = make_float4(
            __expf(An[q * 4 + 0] * sumd), __expf(An[q * 4 + 1] * sumd),
            __expf(An[q * 4 + 2] * sumd), __expf(An[q * 4 + 3] * sumd));
        *(float4*)&h_end[o + q * 4] = make_float4(h[q * 4 + 0], h[q * 4 + 1],
                                                  h[q * 4 + 2], h[q * 4 + 3]);
    }
}

__global__ __launch_bounds__(256) void scan_b(const float* __restrict__ a_cum,
                                              const float* __restrict__ h_end,
                                              float* __restrict__ h_start) {
    const int g = blockIdx.x * 256 + threadIdx.x;  // BB*DINNER*DSTATE = 32768
    const int n = g & 15, d = (g >> 4) & 511, b = g >> 13;
    float hs = 0.f;
#pragma unroll 8
    for (int c = 0; c < NC; ++c) {
        const size_t idx = ((size_t)(c * BB + b) * DINNER + d) * 16 + n;
        h_start[idx] = hs;
        hs = fmaf(a_cum[idx], hs, h_end[idx]);
    }
}

__global__ __launch_bounds__(256) void scan_c(const ushort* __restrict__ ub,
                                              const ushort* __restrict__ zb,
                                              const float* __restrict__ x_dbl,
                                              const float* __restrict__ A_log,
                                              const float* __restrict__ W_dt,
                                              const float* __restrict__ b_dt,
                                              const float* __restrict__ Dskip,
                                              const float* __restrict__ h_start,
                                              ushort* __restrict__ ygb) {
    const int g = blockIdx.x * 256 + threadIdx.x;
    const int d = g & 511, bc = g >> 9;
    const int b = bc & 3, c = bc >> 2;

    float An[16], Wd[16];
    {
        const float4* ap = (const float4*)&A_log[d * 16];
        const float4* wp = (const float4*)&W_dt[d * 16];
#pragma unroll
        for (int q = 0; q < 4; ++q) {
            const float4 v = ap[q];
            An[q * 4 + 0] = -expf(v.x); An[q * 4 + 1] = -expf(v.y);
            An[q * 4 + 2] = -expf(v.z); An[q * 4 + 3] = -expf(v.w);
            const float4 w = wp[q];
            Wd[q * 4 + 0] = w.x; Wd[q * 4 + 1] = w.y;
            Wd[q * 4 + 2] = w.z; Wd[q * 4 + 3] = w.w;
        }
    }
    const float bd = b_dt[d];
    float h[16];
    {
        const size_t o = ((size_t)(c * BB + b) * DINNER + d) * 16;
#pragma unroll
        for (int q = 0; q < 4; ++q) {
            const float4 v = *(const float4*)&h_start[o + q * 4];
            h[q * 4 + 0] = v.x; h[q * 4 + 1] = v.y;
            h[q * 4 + 2] = v.z; h[q * 4 + 3] = v.w;
        }
    }
    const float dsk = Dskip[d];

    const size_t row0 = (size_t)b * LL + (size_t)c * LC;
    ushort pu = ub[row0 * 512 + d];
    ushort pz = zb[row0 * 512 + d];
    float4 pD[4], pB[4], pC[4];
    {
        const float4* xp = (const float4*)&x_dbl[row0 * NXP];
#pragma unroll
        for (int q = 0; q < 4; ++q) { pD[q] = xp[q]; pB[q] = xp[4 + q]; pC[q] = xp[8 + q]; }
    }

    for (int i = 0; i < LC; ++i) {
        const size_t crow = row0 + i;
        const float uu = bf2f(pu), zz = bf2f(pz);
        float Dv[16] = {pD[0].x, pD[0].y, pD[0].z, pD[0].w,
                        pD[1].x, pD[1].y, pD[1].z, pD[1].w,
                        pD[2].x, pD[2].y, pD[2].z, pD[2].w,
                        pD[3].x, pD[3].y, pD[3].z, pD[3].w};
        float Bv[16] = {pB[0].x, pB[0].y, pB[0].z, pB[0].w,
                        pB[1].x, pB[1].y, pB[1].z, pB[1].w,
                        pB[2].x, pB[2].y, pB[2].z, pB[2].w,
                        pB[3].x, pB[3].y, pB[3].z, pB[3].w};
        float Cv[16] = {pC[0].x, pC[0].y, pC[0].z, pC[0].w,
                        pC[1].x, pC[1].y, pC[1].z, pC[1].w,
                        pC[2].x, pC[2].y, pC[2].z, pC[2].w,
                        pC[3].x, pC[3].y, pC[3].z, pC[3].w};
        if (i + 1 < LC) {  // wave-uniform branch
            const size_t row = crow + 1;
            pu = ub[row * 512 + d];
            pz = zb[row * 512 + d];
            const float4* xp = (const float4*)&x_dbl[row * NXP];
#pragma unroll
            for (int q = 0; q < 4; ++q) { pD[q] = xp[q]; pB[q] = xp[4 + q]; pC[q] = xp[8 + q]; }
        }
        float s = bd;
#pragma unroll
        for (int n = 0; n < 16; ++n) s = fmaf(Dv[n], Wd[n], s);
        const float dlt = (s > 20.f) ? s : __logf(1.f + __expf(s));
        const float du = dlt * uu;
#pragma unroll
        for (int n = 0; n < 16; ++n)
            h[n] = fmaf(__expf(dlt * An[n]), h[n], du * Bv[n]);
        float y = 0.f;
#pragma unroll
        for (int n = 0; n < 16; ++n) y = fmaf(h[n], Cv[n], y);
        y = fmaf(uu, dsk, y);
        const float sz = zz / (1.f + __expf(-zz));
        ygb[crow * 512 + d] = f2bf(y * sz);
    }
}

// ---------------------------------------------------------------------------
extern "C" void kernel_launch(void* const* d_in, const int* in_sizes, int n_in,
                              void* d_out, int out_size, void* d_ws, size_t ws_size,
                              hipStream_t stream) {
    const float* x      = (const float*)d_in[0];
    const float* W_in   = (const float*)d_in[1];
    const float* conv_w = (const float*)d_in[2];
    const float* conv_b = (const float*)d_in[3];
    const float* W_xp   = (const float*)d_in[4];
    const float* W_dt   = (const float*)d_in[5];
    const float* b_dt   = (const float*)d_in[6];
    const float* A_log  = (const float*)d_in[7];
    const float* Dskip  = (const float*)d_in[8];
    const float* W_out  = (const float*)d_in[9];
    float* out = (float*)d_out;

    // workspace layout (~74 MB, no aliasing)
    ushort* xb     = (ushort*)d_ws;                 // 8192*256 bf16
    ushort* ub     = xb + (size_t)MROWS * DMODEL;   // 8192*512 bf16
    ushort* zb     = ub + (size_t)MROWS * 512;
    ushort* ygb    = zb + (size_t)MROWS * 512;
    ushort* W_in_b = ygb + (size_t)MROWS * 512;     // 1024*256
    ushort* W_xp_b = W_in_b + 1024 * 256;           // 48*512
    ushort* W_ou_b = W_xp_b + 48 * 512;             // 256*512
    float* xu      = (float*)(W_ou_b + 256 * 512);  // 8192*512 fp32 (u pre-conv)
    float* x_dbl   = xu + (size_t)MROWS * 512;      // 8192*48
    float* a_cum   = x_dbl + (size_t)MROWS * NXP;   // 2.1M each
    float* h_end   = a_cum + (size_t)NC * BB * DINNER * DSTATE;
    float* h_start = h_end + (size_t)NC * BB * DINNER * DSTATE;

    // 0) x + weights -> bf16
    cvt_all<<<2456, 256, 0, stream>>>(x, W_in, W_xp, W_out, xb, W_in_b, W_xp_b, W_ou_b);

    // 1) in_proj: u-half -> xu fp32, z-half -> zb bf16
    {
        dim3 grid(16, MROWS / 64);
        in_gemm64<<<grid, 256, 0, stream>>>(xb, W_in_b, xu, zb);
    }
    // 2) conv + SiLU -> ub bf16
    conv_silu<<<(MROWS * 64) / 256, 256, 0, stream>>>(xu, conv_w, conv_b, ub);
    // 3) x_proj: x_dbl = u @ W_xproj^T  [8192,48]
    {
        dim3 grid(1, MROWS / 64);
        gemm_nt64<1><<<grid, 256, 0, stream>>>(ub, W_xp_b, x_dbl, MROWS, NXP, DINNER);
    }
    // 4-6) chunked selective scan (dt_proj+softplus fused) + gating
    scan_a<<<(BB * NC * DINNER) / 256, 256, 0, stream>>>(ub, x_dbl, A_log, W_dt, b_dt,
                                                         a_cum, h_end);
    scan_b<<<(BB * DINNER * DSTATE) / 256, 256, 0, stream>>>(a_cum, h_end, h_start);
    scan_c<<<(BB * NC * DINNER) / 256, 256, 0, stream>>>(ub, zb, x_dbl, A_log, W_dt, b_dt,
                                                         Dskip, h_start, ygb);
    // 7) out_proj: out = yg @ W_out^T  [8192,256]
    {
        dim3 grid(DMODEL / 64, MROWS / 64);
        gemm_nt64<0><<<grid, 256, 0, stream>>>(ygb, W_ou_b, out, MROWS, DMODEL, DINNER);
    }
}